// Round 1
// baseline (552.214 us; speedup 1.0000x reference)
//
#include <hip/hip_runtime.h>
#include <hip/hip_bf16.h>

#define N_NODES 50000
#define K_NB 16
#define E_EDGES 800000
#define B_MOL 1024
#define MAXM_M 48
#define FDIM 9
#define ADIM 10
#define H 64
#define NEG_INF_F (-1e9f)

// ---------------------------------------------------------------------------
// Fold weight matrices:
//   W2[10,64] = W_dist @ Wm_gat      c2[64] = b_dist @ Wm_gat
//   W3[9,64]  = W_emb  @ W_gat       c3[64] = b_emb  @ W_gat
// ---------------------------------------------------------------------------
__global__ __launch_bounds__(64) void k_fold(
    const float* __restrict__ W_emb, const float* __restrict__ b_emb,
    const float* __restrict__ W_dist, const float* __restrict__ b_dist,
    const float* __restrict__ W_gat, const float* __restrict__ Wm_gat,
    float* __restrict__ W2, float* __restrict__ c2,
    float* __restrict__ W3, float* __restrict__ c3)
{
    int h = threadIdx.x;  // 64 threads
    for (int j = 0; j < ADIM; ++j) {
        float acc = 0.f;
        for (int t = 0; t < H; ++t) acc += W_dist[j * H + t] * Wm_gat[t * H + h];
        W2[j * H + h] = acc;
    }
    {
        float acc = 0.f;
        for (int t = 0; t < H; ++t) acc += b_dist[t] * Wm_gat[t * H + h];
        c2[h] = acc;
    }
    for (int j = 0; j < FDIM; ++j) {
        float acc = 0.f;
        for (int t = 0; t < H; ++t) acc += W_emb[j * H + t] * W_gat[t * H + h];
        W3[j * H + h] = acc;
    }
    {
        float acc = 0.f;
        for (int t = 0; t < H; ++t) acc += b_emb[t] * W_gat[t * H + h];
        c3[h] = acc;
    }
}

// ---------------------------------------------------------------------------
// WGh1[N+1,64]: row 0 = 0; row n+1 = tf[n] @ W3 + c3   (== hp1 @ W_gat)
// One wave (64 lanes) per node; lane = output feature.
// ---------------------------------------------------------------------------
__global__ __launch_bounds__(256) void k_wgh1(
    const float* __restrict__ tf, const float* __restrict__ W3,
    const float* __restrict__ c3, float* __restrict__ WGh1)
{
    if (blockIdx.x == 0 && threadIdx.x < H) WGh1[threadIdx.x] = 0.f;
    int tid = blockIdx.x * blockDim.x + threadIdx.x;
    int n = tid >> 6;
    int h = tid & 63;
    if (n >= N_NODES) return;
    float acc = c3[h];
#pragma unroll
    for (int j = 0; j < FDIM; ++j) acc += tf[n * FDIM + j] * W3[j * H + h];
    WGh1[(size_t)(n + 1) * H + h] = acc;
}

// ---------------------------------------------------------------------------
// GAT iteration. One wave per node, lane = feature h.
// ITER==1: Wm_k = msg_in[e] @ W2 + c2 (on-the-fly from raw edge features)
// ITER==2: Wm_k = (scope_update_lig[e]>0) ? WhWm[scope_update[e]] : 0
// ---------------------------------------------------------------------------
template <int ITER>
__global__ __launch_bounds__(256) void k_gat(
    const int* __restrict__ sse, const int* __restrict__ bsc,
    const float* __restrict__ WGh,
    const float* __restrict__ fdg, const float* __restrict__ rij,
    const float* __restrict__ W2, const float* __restrict__ c2,
    const int* __restrict__ scope_update, const int* __restrict__ scope_update_lig,
    const float* __restrict__ WhWm,
    const float* __restrict__ a_gat,
    float* __restrict__ hp_out)
{
    int wave = threadIdx.x >> 6;
    int lane = threadIdx.x & 63;
    int n = blockIdx.x * 4 + wave;
    if (n == 0) hp_out[lane] = 0.f;  // zero pad row of output
    if (n >= N_NODES) return;

    float a1 = a_gat[lane];
    float a2 = a_gat[H + lane];

    float w2col[ADIM];
    float c2v = 0.f;
    if (ITER == 1) {
#pragma unroll
        for (int j = 0; j < ADIM; ++j) w2col[j] = W2[j * H + lane];
        c2v = c2[lane];
    }

    // coalesced load of the 16 neighbor / edge indices
    int idx16 = (lane < K_NB) ? sse[n * K_NB + lane] : 0;
    int e16   = (lane < K_NB) ? bsc[n * K_NB + lane] : 0;

    float Sk[K_NB];
    float lg[K_NB];
#pragma unroll
    for (int k = 0; k < K_NB; ++k) {
        int idx = __shfl(idx16, k, 64);
        int e   = __shfl(e16, k, 64);
        float wn = WGh[(size_t)idx * H + lane];
        float wm;
        if (ITER == 1) {
            float fv = 0.f;
            if (lane < FDIM)       fv = fdg[(size_t)e * FDIM + lane];
            else if (lane == FDIM) fv = rij[e];
            wm = c2v;
#pragma unroll
            for (int j = 0; j < ADIM; ++j) wm += __shfl(fv, j, 64) * w2col[j];
        } else {
            int su  = scope_update[e];
            int lig = scope_update_lig[e];
            wm = (lig > 0) ? WhWm[(size_t)su * H + lane] : 0.f;
        }
        Sk[k] = wn + wm;
        float p = wn * a1 + wm * a2;
#pragma unroll
        for (int o = 32; o > 0; o >>= 1) p += __shfl_xor(p, o, 64);
        p = (p > 0.f) ? p : 0.2f * p;          // leaky_relu(0.2)
        lg[k] = (idx == 0) ? NEG_INF_F : p;    // pad mask
    }

    // softmax over 16 logits (replicated across lanes)
    float m = lg[0];
#pragma unroll
    for (int k = 1; k < K_NB; ++k) m = fmaxf(m, lg[k]);
    float s = 0.f;
    float ex[K_NB];
#pragma unroll
    for (int k = 0; k < K_NB; ++k) { ex[k] = __expf(lg[k] - m); s += ex[k]; }
    float inv = 1.f / s;
    float acc = 0.f;
#pragma unroll
    for (int k = 0; k < K_NB; ++k) acc += ex[k] * inv * Sk[k];

    float o = (acc > 0.f) ? acc : expm1f(acc);  // elu
    hp_out[(size_t)(n + 1) * H + lane] = o;
}

// ---------------------------------------------------------------------------
// Dense [N+1,64] @ [64,64] pair: WGh = hp@W_gat, WhWm = hp@Wm_gat.
// Weight columns in registers (lane = output feature), grid-stride over rows.
// ---------------------------------------------------------------------------
__global__ __launch_bounds__(256) void k_gemm2(
    const float* __restrict__ hp,
    const float* __restrict__ W_gat, const float* __restrict__ Wm_gat,
    float* __restrict__ WGh, float* __restrict__ WhWm)
{
    int lane = threadIdx.x & 63;
    float wg[H], wm[H];
#pragma unroll
    for (int j = 0; j < H; ++j) {
        wg[j] = W_gat[j * H + lane];
        wm[j] = Wm_gat[j * H + lane];
    }
    int row = blockIdx.x * 4 + (threadIdx.x >> 6);
    int stride = gridDim.x * 4;
    for (; row <= N_NODES; row += stride) {
        float hv = hp[(size_t)row * H + lane];
        float a = 0.f, b = 0.f;
#pragma unroll
        for (int j = 0; j < H; ++j) {
            float hj = __shfl(hv, j, 64);
            a += hj * wg[j];
            b += hj * wm[j];
        }
        WGh[(size_t)row * H + lane] = a;
        WhWm[(size_t)row * H + lane] = b;
    }
}

// ---------------------------------------------------------------------------
// out[b] = sum_m hp[l_scope[b,m]]   (pad index 0 gathers the zero row)
// ---------------------------------------------------------------------------
__global__ __launch_bounds__(256) void k_out(
    const int* __restrict__ l_scope, const float* __restrict__ hp,
    float* __restrict__ out)
{
    int wave = threadIdx.x >> 6;
    int lane = threadIdx.x & 63;
    int b = blockIdx.x * 4 + wave;
    if (b >= B_MOL) return;
    int idx48 = (lane < MAXM_M) ? l_scope[b * MAXM_M + lane] : 0;
    float acc = 0.f;
#pragma unroll
    for (int m = 0; m < MAXM_M; ++m) {
        int idx = __shfl(idx48, m, 64);
        acc += hp[(size_t)idx * H + lane];
    }
    out[b * H + lane] = acc;
}

extern "C" void kernel_launch(void* const* d_in, const int* in_sizes, int n_in,
                              void* d_out, int out_size, void* d_ws, size_t ws_size,
                              hipStream_t stream)
{
    const float* tf     = (const float*)d_in[0];
    const float* fdg    = (const float*)d_in[1];
    const float* rij    = (const float*)d_in[2];
    const int*   sse    = (const int*)d_in[3];
    const int*   bsc    = (const int*)d_in[4];
    const int*   lsc    = (const int*)d_in[5];
    const int*   su     = (const int*)d_in[6];
    const int*   sul    = (const int*)d_in[7];
    const float* W_emb  = (const float*)d_in[8];
    const float* b_emb  = (const float*)d_in[9];
    const float* W_dist = (const float*)d_in[10];
    const float* b_dist = (const float*)d_in[11];
    const float* W_gat  = (const float*)d_in[12];
    const float* Wm_gat = (const float*)d_in[13];
    const float* a_gat  = (const float*)d_in[14];
    float* out = (float*)d_out;

    float* ws = (float*)d_ws;
    float* W2 = ws;            // 640
    float* c2 = ws + 640;      // 64
    float* W3 = ws + 704;      // 576
    float* c3 = ws + 1280;     // 64
    const size_t RSZ = (size_t)(N_NODES + 1) * H;  // 3,200,064 floats
    float* bufA = ws + 2048;        // WGh1, then WGh2
    float* bufB = bufA + RSZ;       // hp2, then hp3
    float* bufC = bufB + RSZ;       // WhWm2

    k_fold<<<dim3(1), dim3(64), 0, stream>>>(W_emb, b_emb, W_dist, b_dist,
                                             W_gat, Wm_gat, W2, c2, W3, c3);

    k_wgh1<<<dim3((N_NODES * 64 + 255) / 256), dim3(256), 0, stream>>>(tf, W3, c3, bufA);

    dim3 gat_grid((N_NODES + 3) / 4);
    k_gat<1><<<gat_grid, dim3(256), 0, stream>>>(
        sse, bsc, bufA, fdg, rij, W2, c2, su, sul, bufC, a_gat, bufB);

    k_gemm2<<<dim3(1024), dim3(256), 0, stream>>>(bufB, W_gat, Wm_gat, bufA, bufC);

    k_gat<2><<<gat_grid, dim3(256), 0, stream>>>(
        sse, bsc, bufA, fdg, rij, W2, c2, su, sul, bufC, a_gat, bufB);

    k_out<<<dim3(B_MOL / 4), dim3(256), 0, stream>>>(lsc, bufB, out);
}

// Round 2
// 307.095 us; speedup vs baseline: 1.7982x; 1.7982x over previous
//
#include <hip/hip_runtime.h>
#include <hip/hip_bf16.h>

#define N_NODES 50000
#define K_NB 16
#define E_EDGES 800000
#define B_MOL 1024
#define MAXM_M 48
#define FDIM 9
#define ADIM 10
#define H 64
#define NEG_INF_F (-1e9f)

__device__ inline float readlane_f(float v, int l) {
    return __int_as_float(__builtin_amdgcn_readlane(__float_as_int(v), l));
}
__device__ inline int readlane_i(int v, int l) {
    return __builtin_amdgcn_readlane(v, l);
}

// ---------------------------------------------------------------------------
// Fold weights:
//   W2[10,64] = W_dist @ Wm_gat     c2[64] = b_dist @ Wm_gat
//   W3[9,64]  = W_emb  @ W_gat      c3[64] = b_emb  @ W_gat
//   wa[10]    = W2 @ a2  (= W_dist @ (Wm_gat @ a2))     ca = c2 . a2
// 6 blocks x 256; thread-per-output, plus one special wave for wa/ca.
// ---------------------------------------------------------------------------
__global__ __launch_bounds__(256) void k_fold(
    const float* __restrict__ W_emb, const float* __restrict__ b_emb,
    const float* __restrict__ W_dist, const float* __restrict__ b_dist,
    const float* __restrict__ W_gat, const float* __restrict__ Wm_gat,
    const float* __restrict__ a_gat,
    float* __restrict__ W2, float* __restrict__ c2,
    float* __restrict__ W3, float* __restrict__ c3,
    float* __restrict__ wa, float* __restrict__ ca)
{
    int tid = blockIdx.x * 256 + threadIdx.x;
    if (tid < 640) {                       // W2
        int j = tid >> 6, h = tid & 63;
        float acc = 0.f;
        for (int t = 0; t < H; ++t) acc += W_dist[j * H + t] * Wm_gat[t * H + h];
        W2[tid] = acc;
    } else if (tid < 704) {                // c2
        int h = tid - 640;
        float acc = 0.f;
        for (int t = 0; t < H; ++t) acc += b_dist[t] * Wm_gat[t * H + h];
        c2[h] = acc;
    } else if (tid < 1280) {               // W3
        int q = tid - 704, j = q >> 6, h = q & 63;
        float acc = 0.f;
        for (int t = 0; t < H; ++t) acc += W_emb[j * H + t] * W_gat[t * H + h];
        W3[q] = acc;
    } else if (tid < 1344) {               // c3
        int h = tid - 1280;
        float acc = 0.f;
        for (int t = 0; t < H; ++t) acc += b_emb[t] * W_gat[t * H + h];
        c3[h] = acc;
    } else if (tid < 1408) {               // special wave: wa, ca
        int lane = tid - 1344;
        float v = 0.f;                     // v[lane] = Wm_gat[lane,:] . a2
        for (int h = 0; h < H; ++h) v += Wm_gat[lane * H + h] * a_gat[H + h];
        float acc = 0.f;
        for (int t = 0; t < H; ++t) {
            float vt = readlane_f(v, t);
            if (lane < ADIM)       acc += W_dist[lane * H + t] * vt;
            else if (lane == ADIM) acc += b_dist[t] * vt;
        }
        if (lane < ADIM)       wa[lane] = acc;
        else if (lane == ADIM) ca[0] = acc;
    }
}

// ---------------------------------------------------------------------------
// WGh1[N+1,64]: row0=0; row n+1 = tf[n]@W3 + c3  (== hp1 @ W_gat)
// also t1[row] = WGh1[row,:] . a1
// ---------------------------------------------------------------------------
__global__ __launch_bounds__(256) void k_wgh1(
    const float* __restrict__ tf, const float* __restrict__ W3,
    const float* __restrict__ c3, const float* __restrict__ a_gat,
    float* __restrict__ WGh1, float* __restrict__ t1)
{
    int tid = blockIdx.x * blockDim.x + threadIdx.x;
    if (blockIdx.x == 0 && threadIdx.x < H) WGh1[threadIdx.x] = 0.f;
    if (tid == 0) t1[0] = 0.f;
    int n = tid >> 6;
    int h = tid & 63;
    if (n >= N_NODES) return;
    float acc = c3[h];
#pragma unroll
    for (int j = 0; j < FDIM; ++j) acc += tf[n * FDIM + j] * W3[j * H + h];
    WGh1[(size_t)(n + 1) * H + h] = acc;
    float tv = acc * a_gat[h];
#pragma unroll
    for (int o = 32; o > 0; o >>= 1) tv += __shfl_xor(tv, o, 64);
    if (h == 0) t1[n + 1] = tv;
}

// ---------------------------------------------------------------------------
// elog[e] = msg_in[e] . wa + ca   (a2-dot of the iter-1 message row)
// ---------------------------------------------------------------------------
__global__ __launch_bounds__(256) void k_elog(
    const float* __restrict__ fdg, const float* __restrict__ rij,
    const float* __restrict__ wa, const float* __restrict__ ca,
    float* __restrict__ elog)
{
    int e = blockIdx.x * 256 + threadIdx.x;
    if (e >= E_EDGES) return;
    float acc = ca[0] + rij[e] * wa[FDIM];
#pragma unroll
    for (int j = 0; j < FDIM; ++j) acc += fdg[(size_t)e * FDIM + j] * wa[j];
    elog[e] = acc;
}

// ---------------------------------------------------------------------------
// GAT iteration, one wave per node, lane = feature.
// Logits via precomputed scalar dots -> 16-lane softmax (no 64-lane butterfly).
// ITER1: Wm deferred: fr = sum_k alpha_k * rawfeat_k, then fr@W2 + c2.
// ITER2: Wm row gather from WhWm with masked edges redirected to zero row 0.
// ---------------------------------------------------------------------------
template <int ITER>
__global__ __launch_bounds__(256) void k_gat(
    const int* __restrict__ sse, const int* __restrict__ bsc,
    const float* __restrict__ WGh, const float* __restrict__ t1,
    const float* __restrict__ elog,
    const float* __restrict__ fdg, const float* __restrict__ rij,
    const float* __restrict__ W2, const float* __restrict__ c2,
    const int* __restrict__ scope_update, const int* __restrict__ scope_update_lig,
    const float* __restrict__ t2, const float* __restrict__ WhWm,
    float* __restrict__ hp_out)
{
    int wave = threadIdx.x >> 6;
    int lane = threadIdx.x & 63;
    int n = blockIdx.x * 4 + wave;
    if (n == 0) hp_out[lane] = 0.f;        // zero pad row of output
    if (n >= N_NODES) return;

    // lanes 0..15 own neighbor k = lane
    int kidx = 0, ke = 0, ksu = 0;
    float lg = NEG_INF_F;
    if (lane < K_NB) {
        kidx = sse[n * K_NB + lane];
        ke   = bsc[n * K_NB + lane];
        float g2;
        if (ITER == 1) {
            g2 = elog[ke];
        } else {
            int lig = scope_update_lig[ke];
            ksu = (lig > 0) ? scope_update[ke] : 0;   // row 0 of WhWm is zero
            g2 = t2[ksu];
        }
        float p = t1[kidx] + g2;
        p = (p > 0.f) ? p : 0.2f * p;      // leaky_relu(0.2)
        lg = (kidx == 0) ? NEG_INF_F : p;  // pad mask
    }
    // softmax across the 16-lane group (xor masks < 16 stay in-group)
    float m = lg;
#pragma unroll
    for (int o = 8; o > 0; o >>= 1) m = fmaxf(m, __shfl_xor(m, o, 64));
    float ex = __expf(lg - m);
    float s = ex;
#pragma unroll
    for (int o = 8; o > 0; o >>= 1) s += __shfl_xor(s, o, 64);
    float alpha = ex / s;                  // lane k holds alpha_k (k<16)

    float acc = 0.f;
    float fr = 0.f;                        // ITER1: alpha-weighted raw feature row
#pragma unroll
    for (int k = 0; k < K_NB; ++k) {
        int idx  = readlane_i(kidx, k);
        float ak = readlane_f(alpha, k);
        float wn = WGh[(size_t)idx * H + lane];
        if (ITER == 1) {
            int e = readlane_i(ke, k);
            float fv = 0.f;
            if (lane < FDIM)       fv = fdg[(size_t)e * FDIM + lane];
            else if (lane == FDIM) fv = rij[e];
            fr  += ak * fv;
            acc += ak * wn;
        } else {
            int sk = readlane_i(ksu, k);
            acc += ak * (wn + WhWm[(size_t)sk * H + lane]);
        }
    }
    if (ITER == 1) {
        float wmacc = c2[lane];
#pragma unroll
        for (int j = 0; j < ADIM; ++j)
            wmacc += readlane_f(fr, j) * W2[j * H + lane];
        acc += wmacc;
    }
    float o = (acc > 0.f) ? acc : expm1f(acc);   // elu
    hp_out[(size_t)(n + 1) * H + lane] = o;
}

// ---------------------------------------------------------------------------
// Dense [N+1,64]@[64,64] pair + per-row a-dots:
//   WGh = hp@W_gat (t1 = row . a1), WhWm = hp@Wm_gat (t2 = row . a2)
// ---------------------------------------------------------------------------
__global__ __launch_bounds__(256) void k_gemm2(
    const float* __restrict__ hp,
    const float* __restrict__ W_gat, const float* __restrict__ Wm_gat,
    const float* __restrict__ a_gat,
    float* __restrict__ WGh, float* __restrict__ WhWm,
    float* __restrict__ t1, float* __restrict__ t2)
{
    int lane = threadIdx.x & 63;
    float wg[H], wm[H];
#pragma unroll
    for (int j = 0; j < H; ++j) {
        wg[j] = W_gat[j * H + lane];
        wm[j] = Wm_gat[j * H + lane];
    }
    float a1 = a_gat[lane], a2 = a_gat[H + lane];
    int row = blockIdx.x * 4 + (threadIdx.x >> 6);
    int stride = gridDim.x * 4;
    for (; row <= N_NODES; row += stride) {
        float hv = hp[(size_t)row * H + lane];
        float a = 0.f, b = 0.f;
#pragma unroll
        for (int j = 0; j < H; ++j) {
            float hj = readlane_f(hv, j);
            a += hj * wg[j];
            b += hj * wm[j];
        }
        WGh[(size_t)row * H + lane]  = a;
        WhWm[(size_t)row * H + lane] = b;
        float ta = a * a1, tb = b * a2;
#pragma unroll
        for (int o = 32; o > 0; o >>= 1) {
            ta += __shfl_xor(ta, o, 64);
            tb += __shfl_xor(tb, o, 64);
        }
        if (lane == 0) { t1[row] = ta; t2[row] = tb; }
    }
}

// ---------------------------------------------------------------------------
// out[b] = sum_m hp[l_scope[b,m]]
// ---------------------------------------------------------------------------
__global__ __launch_bounds__(256) void k_out(
    const int* __restrict__ l_scope, const float* __restrict__ hp,
    float* __restrict__ out)
{
    int wave = threadIdx.x >> 6;
    int lane = threadIdx.x & 63;
    int b = blockIdx.x * 4 + wave;
    if (b >= B_MOL) return;
    int idx48 = (lane < MAXM_M) ? l_scope[b * MAXM_M + lane] : 0;
    float acc = 0.f;
#pragma unroll
    for (int m = 0; m < MAXM_M; ++m) {
        int idx = readlane_i(idx48, m);
        acc += hp[(size_t)idx * H + lane];
    }
    out[b * H + lane] = acc;
}

extern "C" void kernel_launch(void* const* d_in, const int* in_sizes, int n_in,
                              void* d_out, int out_size, void* d_ws, size_t ws_size,
                              hipStream_t stream)
{
    const float* tf     = (const float*)d_in[0];
    const float* fdg    = (const float*)d_in[1];
    const float* rij    = (const float*)d_in[2];
    const int*   sse    = (const int*)d_in[3];
    const int*   bsc    = (const int*)d_in[4];
    const int*   lsc    = (const int*)d_in[5];
    const int*   su     = (const int*)d_in[6];
    const int*   sul    = (const int*)d_in[7];
    const float* W_emb  = (const float*)d_in[8];
    const float* b_emb  = (const float*)d_in[9];
    const float* W_dist = (const float*)d_in[10];
    const float* b_dist = (const float*)d_in[11];
    const float* W_gat  = (const float*)d_in[12];
    const float* Wm_gat = (const float*)d_in[13];
    const float* a_gat  = (const float*)d_in[14];
    float* out = (float*)d_out;

    float* ws = (float*)d_ws;
    float* W2 = ws;              // 640
    float* c2 = ws + 640;        // 64
    float* W3 = ws + 704;        // 576
    float* c3 = ws + 1280;       // 64
    float* wa = ws + 1344;       // 10 (pad 16)
    float* ca = ws + 1360;       // 1
    float* t1 = ws + 2048;                   // N+1
    float* t2 = t1 + (N_NODES + 1);          // N+1
    const size_t RSZ = (size_t)(N_NODES + 1) * H;
    float* bufA = ws + 2048 + 2 * (N_NODES + 1) + 62;  // WGh1 -> WGh2
    float* bufB = bufA + RSZ;                          // hp2 -> hp3
    float* bufC = bufB + RSZ;                          // elog (phase 1) -> WhWm2
    float* elog = bufC;                                // E <= RSZ

    k_fold<<<dim3(6), dim3(256), 0, stream>>>(W_emb, b_emb, W_dist, b_dist,
                                              W_gat, Wm_gat, a_gat,
                                              W2, c2, W3, c3, wa, ca);

    k_wgh1<<<dim3((N_NODES * 64 + 255) / 256), dim3(256), 0, stream>>>(
        tf, W3, c3, a_gat, bufA, t1);

    k_elog<<<dim3((E_EDGES + 255) / 256), dim3(256), 0, stream>>>(
        fdg, rij, wa, ca, elog);

    dim3 gat_grid((N_NODES + 3) / 4);
    k_gat<1><<<gat_grid, dim3(256), 0, stream>>>(
        sse, bsc, bufA, t1, elog, fdg, rij, W2, c2, su, sul, t2, bufC, bufB);

    k_gemm2<<<dim3(1024), dim3(256), 0, stream>>>(
        bufB, W_gat, Wm_gat, a_gat, bufA, bufC, t1, t2);

    k_gat<2><<<gat_grid, dim3(256), 0, stream>>>(
        sse, bsc, bufA, t1, elog, fdg, rij, W2, c2, su, sul, t2, bufC, bufB);

    k_out<<<dim3(B_MOL / 4), dim3(256), 0, stream>>>(lsc, bufB, out);
}

// Round 3
// 257.019 us; speedup vs baseline: 2.1485x; 1.1948x over previous
//
#include <hip/hip_runtime.h>
#include <hip/hip_bf16.h>

#define N_NODES 50000
#define K_NB 16
#define E_EDGES 800000
#define B_MOL 1024
#define MAXM_M 48
#define FDIM 9
#define ADIM 10
#define H 64
#define NEG_INF_F (-1e9f)
#define NODE_BLOCKS 12500   /* 4 nodes per 256-thread block */
#define EDGE_BLOCKS 3125    /* 256 edges per block */

__device__ inline float readlane_f(float v, int l) {
    return __int_as_float(__builtin_amdgcn_readlane(__float_as_int(v), l));
}
__device__ inline int readlane_i(int v, int l) {
    return __builtin_amdgcn_readlane(v, l);
}
__device__ inline float bf2f(unsigned short u) {
    return __uint_as_float(((unsigned)u) << 16);
}
__device__ inline unsigned short f2bf(float f) {   // round-to-nearest-even
    unsigned x = __float_as_uint(f);
    return (unsigned short)((x + 0x7fffu + ((x >> 16) & 1u)) >> 16);
}

// ---------------------------------------------------------------------------
// Fold weights:
//   W2[10,64] = W_dist @ Wm_gat     c2[64] = b_dist @ Wm_gat
//   W3[9,64]  = W_emb  @ W_gat      c3[64] = b_emb  @ W_gat
//   wa[10]    = W_dist @ (Wm_gat @ a2)      ca = b_dist . (Wm_gat @ a2)
// ---------------------------------------------------------------------------
__global__ __launch_bounds__(256) void k_fold(
    const float* __restrict__ W_emb, const float* __restrict__ b_emb,
    const float* __restrict__ W_dist, const float* __restrict__ b_dist,
    const float* __restrict__ W_gat, const float* __restrict__ Wm_gat,
    const float* __restrict__ a_gat,
    float* __restrict__ W2, float* __restrict__ c2,
    float* __restrict__ W3, float* __restrict__ c3,
    float* __restrict__ wa, float* __restrict__ ca)
{
    int tid = blockIdx.x * 256 + threadIdx.x;
    if (tid < 640) {                       // W2
        int j = tid >> 6, h = tid & 63;
        float acc = 0.f;
        for (int t = 0; t < H; ++t) acc += W_dist[j * H + t] * Wm_gat[t * H + h];
        W2[tid] = acc;
    } else if (tid < 704) {                // c2
        int h = tid - 640;
        float acc = 0.f;
        for (int t = 0; t < H; ++t) acc += b_dist[t] * Wm_gat[t * H + h];
        c2[h] = acc;
    } else if (tid < 1280) {               // W3
        int q = tid - 704, j = q >> 6, h = q & 63;
        float acc = 0.f;
        for (int t = 0; t < H; ++t) acc += W_emb[j * H + t] * W_gat[t * H + h];
        W3[q] = acc;
    } else if (tid < 1344) {               // c3
        int h = tid - 1280;
        float acc = 0.f;
        for (int t = 0; t < H; ++t) acc += b_emb[t] * W_gat[t * H + h];
        c3[h] = acc;
    } else if (tid < 1408) {               // special wave: wa, ca
        int lane = tid - 1344;
        float v = 0.f;                     // v[lane] = Wm_gat[lane,:] . a2
        for (int h = 0; h < H; ++h) v += Wm_gat[lane * H + h] * a_gat[H + h];
        float acc = 0.f;
        for (int t = 0; t < H; ++t) {
            float vt = readlane_f(v, t);
            if (lane < ADIM)       acc += W_dist[lane * H + t] * vt;
            else if (lane == ADIM) acc += b_dist[t] * vt;
        }
        if (lane < ADIM)       wa[lane] = acc;
        else if (lane == ADIM) ca[0] = acc;
    }
}

// ---------------------------------------------------------------------------
// Fused pre-pass.
// Node section: WGh1 row n+1 = tf[n]@W3 + c3 (stored bf16), t1[row]=row.a1
// Edge section: pack emsg[e] (32B): ushort[0..9]=bf16(f0..f8,rij),
//               float elog at byte 20; and sue[e] = sul>0 ? su : 0
// ---------------------------------------------------------------------------
__global__ __launch_bounds__(256) void k_pre(
    const float* __restrict__ tf, const float* __restrict__ fdg,
    const float* __restrict__ rij,
    const int* __restrict__ su, const int* __restrict__ sul,
    const float* __restrict__ W3, const float* __restrict__ c3,
    const float* __restrict__ wa, const float* __restrict__ ca,
    const float* __restrict__ a_gat,
    unsigned short* __restrict__ WGh16, float* __restrict__ t1,
    unsigned short* __restrict__ emsg, int* __restrict__ sue)
{
    int bid = blockIdx.x;
    if (bid < NODE_BLOCKS) {
        int tid = bid * 256 + threadIdx.x;
        int n = tid >> 6, h = tid & 63;
        if (tid < 64) { WGh16[tid] = 0; if (tid == 0) t1[0] = 0.f; }
        float acc = c3[h];
#pragma unroll
        for (int j = 0; j < FDIM; ++j) acc += tf[n * FDIM + j] * W3[j * H + h];
        WGh16[(size_t)(n + 1) * H + h] = f2bf(acc);
        float tv = acc * a_gat[h];
#pragma unroll
        for (int o = 32; o > 0; o >>= 1) tv += __shfl_xor(tv, o, 64);
        if (h == 0) t1[n + 1] = tv;
    } else {
        int e = (bid - NODE_BLOCKS) * 256 + threadIdx.x;
        float f[ADIM];
#pragma unroll
        for (int j = 0; j < FDIM; ++j) f[j] = fdg[(size_t)e * FDIM + j];
        f[FDIM] = rij[e];
        float acc = ca[0];
#pragma unroll
        for (int j = 0; j < ADIM; ++j) acc += f[j] * wa[j];
        unsigned rec[8];
#pragma unroll
        for (int j = 0; j < 5; ++j)
            rec[j] = (unsigned)f2bf(f[2 * j]) | ((unsigned)f2bf(f[2 * j + 1]) << 16);
        rec[5] = __float_as_uint(acc);
        rec[6] = 0; rec[7] = 0;
        uint4* dst = (uint4*)(emsg + (size_t)e * 16);
        dst[0] = make_uint4(rec[0], rec[1], rec[2], rec[3]);
        dst[1] = make_uint4(rec[4], rec[5], rec[6], rec[7]);
        sue[e] = (sul[e] > 0) ? su[e] : 0;
    }
}

// ---------------------------------------------------------------------------
// GAT iteration, one wave per node, lane = feature.
// ITER1: elog from packed record; Wm deferred via fr@W2+c2 (bf16 features).
// ITER2: Wm = WhWm16[sue[e]] (row 0 is zero), logit via t2[sue[e]].
// ---------------------------------------------------------------------------
template <int ITER>
__global__ __launch_bounds__(256) void k_gat(
    const int* __restrict__ sse, const int* __restrict__ bsc,
    const unsigned short* __restrict__ WGh16, const float* __restrict__ t1,
    const unsigned short* __restrict__ emsg,
    const float* __restrict__ W2, const float* __restrict__ c2,
    const int* __restrict__ sue, const float* __restrict__ t2,
    const unsigned short* __restrict__ WhWm16,
    float* __restrict__ hp_out)
{
    int wave = threadIdx.x >> 6;
    int lane = threadIdx.x & 63;
    int n = blockIdx.x * 4 + wave;
    if (n == 0) hp_out[lane] = 0.f;        // zero pad row of output
    if (n >= N_NODES) return;

    // lanes 0..15 own neighbor k = lane
    int kidx = 0, ke = 0, ksu = 0;
    float lg = NEG_INF_F;
    if (lane < K_NB) {
        kidx = sse[n * K_NB + lane];
        ke   = bsc[n * K_NB + lane];
        float g2;
        if (ITER == 1) {
            g2 = __uint_as_float(*(const unsigned*)(emsg + (size_t)ke * 16 + 10));
        } else {
            ksu = sue[ke];
            g2 = t2[ksu];
        }
        float p = t1[kidx] + g2;
        p = (p > 0.f) ? p : 0.2f * p;      // leaky_relu(0.2)
        lg = (kidx == 0) ? NEG_INF_F : p;  // pad mask
    }
    float m = lg;
#pragma unroll
    for (int o = 8; o > 0; o >>= 1) m = fmaxf(m, __shfl_xor(m, o, 64));
    float ex = __expf(lg - m);
    float s = ex;
#pragma unroll
    for (int o = 8; o > 0; o >>= 1) s += __shfl_xor(s, o, 64);
    float alpha = ex / s;

    float acc = 0.f;
    float fr = 0.f;
#pragma unroll
    for (int k = 0; k < K_NB; ++k) {
        int idx  = readlane_i(kidx, k);
        float ak = readlane_f(alpha, k);
        float wn = bf2f(WGh16[(size_t)idx * H + lane]);
        if (ITER == 1) {
            int e = readlane_i(ke, k);
            float fv = (lane < ADIM) ? bf2f(emsg[(size_t)e * 16 + lane]) : 0.f;
            fr  += ak * fv;
            acc += ak * wn;
        } else {
            int sk = readlane_i(ksu, k);
            acc += ak * (wn + bf2f(WhWm16[(size_t)sk * H + lane]));
        }
    }
    if (ITER == 1) {
        float wmacc = c2[lane];
#pragma unroll
        for (int j = 0; j < ADIM; ++j)
            wmacc += readlane_f(fr, j) * W2[j * H + lane];
        acc += wmacc;
    }
    float o = (acc > 0.f) ? acc : expm1f(acc);   // elu
    hp_out[(size_t)(n + 1) * H + lane] = o;
}

// ---------------------------------------------------------------------------
// WGh2 = hp2@W_gat (bf16, t1 = f32 row.a1), WhWm2 = hp2@Wm_gat (bf16, t2)
// ---------------------------------------------------------------------------
__global__ __launch_bounds__(256) void k_gemm2(
    const float* __restrict__ hp,
    const float* __restrict__ W_gat, const float* __restrict__ Wm_gat,
    const float* __restrict__ a_gat,
    unsigned short* __restrict__ WGh16, unsigned short* __restrict__ WhWm16,
    float* __restrict__ t1, float* __restrict__ t2)
{
    int lane = threadIdx.x & 63;
    float wg[H], wm[H];
#pragma unroll
    for (int j = 0; j < H; ++j) {
        wg[j] = W_gat[j * H + lane];
        wm[j] = Wm_gat[j * H + lane];
    }
    float a1 = a_gat[lane], a2 = a_gat[H + lane];
    int row = blockIdx.x * 4 + (threadIdx.x >> 6);
    int stride = gridDim.x * 4;
    for (; row <= N_NODES; row += stride) {
        float hv = hp[(size_t)row * H + lane];
        float a = 0.f, b = 0.f;
#pragma unroll
        for (int j = 0; j < H; ++j) {
            float hj = readlane_f(hv, j);
            a += hj * wg[j];
            b += hj * wm[j];
        }
        WGh16[(size_t)row * H + lane]  = f2bf(a);
        WhWm16[(size_t)row * H + lane] = f2bf(b);
        float ta = a * a1, tb = b * a2;
#pragma unroll
        for (int o = 32; o > 0; o >>= 1) {
            ta += __shfl_xor(ta, o, 64);
            tb += __shfl_xor(tb, o, 64);
        }
        if (lane == 0) { t1[row] = ta; t2[row] = tb; }
    }
}

// ---------------------------------------------------------------------------
// out[b] = sum_m hp[l_scope[b,m]]
// ---------------------------------------------------------------------------
__global__ __launch_bounds__(256) void k_out(
    const int* __restrict__ l_scope, const float* __restrict__ hp,
    float* __restrict__ out)
{
    int wave = threadIdx.x >> 6;
    int lane = threadIdx.x & 63;
    int b = blockIdx.x * 4 + wave;
    if (b >= B_MOL) return;
    int idx48 = (lane < MAXM_M) ? l_scope[b * MAXM_M + lane] : 0;
    float acc = 0.f;
#pragma unroll
    for (int m = 0; m < MAXM_M; ++m) {
        int idx = readlane_i(idx48, m);
        acc += hp[(size_t)idx * H + lane];
    }
    out[b * H + lane] = acc;
}

extern "C" void kernel_launch(void* const* d_in, const int* in_sizes, int n_in,
                              void* d_out, int out_size, void* d_ws, size_t ws_size,
                              hipStream_t stream)
{
    const float* tf     = (const float*)d_in[0];
    const float* fdg    = (const float*)d_in[1];
    const float* rij    = (const float*)d_in[2];
    const int*   sse    = (const int*)d_in[3];
    const int*   bsc    = (const int*)d_in[4];
    const int*   lsc    = (const int*)d_in[5];
    const int*   su     = (const int*)d_in[6];
    const int*   sul    = (const int*)d_in[7];
    const float* W_emb  = (const float*)d_in[8];
    const float* b_emb  = (const float*)d_in[9];
    const float* W_dist = (const float*)d_in[10];
    const float* b_dist = (const float*)d_in[11];
    const float* W_gat  = (const float*)d_in[12];
    const float* Wm_gat = (const float*)d_in[13];
    const float* a_gat  = (const float*)d_in[14];
    float* out = (float*)d_out;

    char* base = (char*)d_ws;
    size_t off = 0;
    auto alloc = [&](size_t bytes) {
        char* p = base + off;
        off = (off + bytes + 255) & ~(size_t)255;
        return p;
    };
    float* W2   = (float*)alloc(640 * 4);
    float* c2   = (float*)alloc(64 * 4);
    float* W3   = (float*)alloc(576 * 4);
    float* c3   = (float*)alloc(64 * 4);
    float* wa   = (float*)alloc(16 * 4);
    float* ca   = (float*)alloc(16 * 4);
    float* t1   = (float*)alloc((size_t)(N_NODES + 1) * 4);
    float* t2   = (float*)alloc((size_t)(N_NODES + 1) * 4);
    int*   sue  = (int*)alloc((size_t)E_EDGES * 4);
    unsigned short* WGh16  = (unsigned short*)alloc((size_t)(N_NODES + 1) * H * 2);
    unsigned short* WhWm16 = (unsigned short*)alloc((size_t)(N_NODES + 1) * H * 2);
    float* hp2  = (float*)alloc((size_t)(N_NODES + 1) * H * 4);
    // emsg (25.6MB) and hp3 (12.8MB) alias: emsg dead before k_gat<2> writes hp3
    char*  big  = alloc((size_t)E_EDGES * 32);
    unsigned short* emsg = (unsigned short*)big;
    float* hp3  = (float*)big;

    k_fold<<<dim3(6), dim3(256), 0, stream>>>(W_emb, b_emb, W_dist, b_dist,
                                              W_gat, Wm_gat, a_gat,
                                              W2, c2, W3, c3, wa, ca);

    k_pre<<<dim3(NODE_BLOCKS + EDGE_BLOCKS), dim3(256), 0, stream>>>(
        tf, fdg, rij, su, sul, W3, c3, wa, ca, a_gat, WGh16, t1, emsg, sue);

    dim3 gat_grid((N_NODES + 3) / 4);
    k_gat<1><<<gat_grid, dim3(256), 0, stream>>>(
        sse, bsc, WGh16, t1, emsg, W2, c2, sue, t2, WhWm16, hp2);

    k_gemm2<<<dim3(1024), dim3(256), 0, stream>>>(
        hp2, W_gat, Wm_gat, a_gat, WGh16, WhWm16, t1, t2);

    k_gat<2><<<gat_grid, dim3(256), 0, stream>>>(
        sse, bsc, WGh16, t1, emsg, W2, c2, sue, t2, WhWm16, hp3);

    k_out<<<dim3(B_MOL / 4), dim3(256), 0, stream>>>(lsc, hp3, out);
}

// Round 4
// 254.934 us; speedup vs baseline: 2.1661x; 1.0082x over previous
//
#include <hip/hip_runtime.h>
#include <hip/hip_bf16.h>

#define N_NODES 50000
#define K_NB 16
#define E_EDGES 800000
#define B_MOL 1024
#define MAXM_M 48
#define FDIM 9
#define ADIM 10
#define H 64
#define NEG_INF_F (-1e9f)
#define NODE_BLOCKS 12500   /* 4 nodes per 256-thread block */
#define EDGE_BLOCKS 3125    /* 256 edges per block */

__device__ inline float readlane_f(float v, int l) {
    return __int_as_float(__builtin_amdgcn_readlane(__float_as_int(v), l));
}
__device__ inline int readlane_i(int v, int l) {
    return __builtin_amdgcn_readlane(v, l);
}
__device__ inline float bf2f(unsigned short u) {
    return __uint_as_float(((unsigned)u) << 16);
}
__device__ inline unsigned short f2bf(float f) {   // round-to-nearest-even
    unsigned x = __float_as_uint(f);
    return (unsigned short)((x + 0x7fffu + ((x >> 16) & 1u)) >> 16);
}

// ---------------------------------------------------------------------------
// Fold weights:
//   W2[10,64] = W_dist @ Wm_gat     c2[64] = b_dist @ Wm_gat
//   W3[9,64]  = W_emb  @ W_gat      c3[64] = b_emb  @ W_gat
//   wa[10]    = W_dist @ (Wm_gat @ a2)      ca = b_dist . (Wm_gat @ a2)
// ---------------------------------------------------------------------------
__global__ __launch_bounds__(256) void k_fold(
    const float* __restrict__ W_emb, const float* __restrict__ b_emb,
    const float* __restrict__ W_dist, const float* __restrict__ b_dist,
    const float* __restrict__ W_gat, const float* __restrict__ Wm_gat,
    const float* __restrict__ a_gat,
    float* __restrict__ W2, float* __restrict__ c2,
    float* __restrict__ W3, float* __restrict__ c3,
    float* __restrict__ wa, float* __restrict__ ca)
{
    int tid = blockIdx.x * 256 + threadIdx.x;
    if (tid < 640) {                       // W2
        int j = tid >> 6, h = tid & 63;
        float acc = 0.f;
        for (int t = 0; t < H; ++t) acc += W_dist[j * H + t] * Wm_gat[t * H + h];
        W2[tid] = acc;
    } else if (tid < 704) {                // c2
        int h = tid - 640;
        float acc = 0.f;
        for (int t = 0; t < H; ++t) acc += b_dist[t] * Wm_gat[t * H + h];
        c2[h] = acc;
    } else if (tid < 1280) {               // W3
        int q = tid - 704, j = q >> 6, h = q & 63;
        float acc = 0.f;
        for (int t = 0; t < H; ++t) acc += W_emb[j * H + t] * W_gat[t * H + h];
        W3[q] = acc;
    } else if (tid < 1344) {               // c3
        int h = tid - 1280;
        float acc = 0.f;
        for (int t = 0; t < H; ++t) acc += b_emb[t] * W_gat[t * H + h];
        c3[h] = acc;
    } else if (tid < 1408) {               // special wave: wa, ca
        int lane = tid - 1344;
        float v = 0.f;                     // v[lane] = Wm_gat[lane,:] . a2
        for (int h = 0; h < H; ++h) v += Wm_gat[lane * H + h] * a_gat[H + h];
        float acc = 0.f;
        for (int t = 0; t < H; ++t) {
            float vt = readlane_f(v, t);
            if (lane < ADIM)       acc += W_dist[lane * H + t] * vt;
            else if (lane == ADIM) acc += b_dist[t] * vt;
        }
        if (lane < ADIM)       wa[lane] = acc;
        else if (lane == ADIM) ca[0] = acc;
    }
}

// ---------------------------------------------------------------------------
// Fused pre-pass.
// Node section: WGh1 row n+1 = tf[n]@W3 + c3 (stored bf16), t1[row]=row.a1
// Edge section: pack emsg[e] (32B): ushort[0..9]=bf16(f0..f8,rij),
//               float elog at byte 20; and sue[e] = sul>0 ? su : 0
// ---------------------------------------------------------------------------
__global__ __launch_bounds__(256) void k_pre(
    const float* __restrict__ tf, const float* __restrict__ fdg,
    const float* __restrict__ rij,
    const int* __restrict__ su, const int* __restrict__ sul,
    const float* __restrict__ W3, const float* __restrict__ c3,
    const float* __restrict__ wa, const float* __restrict__ ca,
    const float* __restrict__ a_gat,
    unsigned short* __restrict__ WGh16, float* __restrict__ t1,
    unsigned short* __restrict__ emsg, int* __restrict__ sue)
{
    int bid = blockIdx.x;
    if (bid < NODE_BLOCKS) {
        int tid = bid * 256 + threadIdx.x;
        int n = tid >> 6, h = tid & 63;
        if (tid < 64) { WGh16[tid] = 0; if (tid == 0) t1[0] = 0.f; }
        float acc = c3[h];
#pragma unroll
        for (int j = 0; j < FDIM; ++j) acc += tf[n * FDIM + j] * W3[j * H + h];
        WGh16[(size_t)(n + 1) * H + h] = f2bf(acc);
        float tv = acc * a_gat[h];
#pragma unroll
        for (int o = 32; o > 0; o >>= 1) tv += __shfl_xor(tv, o, 64);
        if (h == 0) t1[n + 1] = tv;
    } else {
        int e = (bid - NODE_BLOCKS) * 256 + threadIdx.x;
        float f[ADIM];
#pragma unroll
        for (int j = 0; j < FDIM; ++j) f[j] = fdg[(size_t)e * FDIM + j];
        f[FDIM] = rij[e];
        float acc = ca[0];
#pragma unroll
        for (int j = 0; j < ADIM; ++j) acc += f[j] * wa[j];
        unsigned rec[8];
#pragma unroll
        for (int j = 0; j < 5; ++j)
            rec[j] = (unsigned)f2bf(f[2 * j]) | ((unsigned)f2bf(f[2 * j + 1]) << 16);
        rec[5] = __float_as_uint(acc);
        rec[6] = 0; rec[7] = 0;
        uint4* dst = (uint4*)(emsg + (size_t)e * 16);
        dst[0] = make_uint4(rec[0], rec[1], rec[2], rec[3]);
        dst[1] = make_uint4(rec[4], rec[5], rec[6], rec[7]);
        sue[e] = (sul[e] > 0) ? su[e] : 0;
    }
}

// ---------------------------------------------------------------------------
// GAT iteration, one wave per node, lane = feature.
// Value-phase gathers prefetched into explicit arrays for MLP (round-4 fix:
// VGPR_Count=24 showed the compiler serialized the 32 row gathers).
// ---------------------------------------------------------------------------
template <int ITER>
__global__ __launch_bounds__(256) void k_gat(
    const int* __restrict__ sse, const int* __restrict__ bsc,
    const unsigned short* __restrict__ WGh16, const float* __restrict__ t1,
    const unsigned short* __restrict__ emsg,
    const float* __restrict__ W2, const float* __restrict__ c2,
    const int* __restrict__ sue, const float* __restrict__ t2,
    const unsigned short* __restrict__ WhWm16,
    float* __restrict__ hp_out)
{
    int wave = threadIdx.x >> 6;
    int lane = threadIdx.x & 63;
    int n = blockIdx.x * 4 + wave;
    if (n == 0) hp_out[lane] = 0.f;        // zero pad row of output
    if (n >= N_NODES) return;

    // lanes 0..15 own neighbor k = lane
    int kidx = 0, ke = 0, ksu = 0;
    float lg = NEG_INF_F;
    if (lane < K_NB) {
        kidx = sse[n * K_NB + lane];
        ke   = bsc[n * K_NB + lane];
        float g2;
        if (ITER == 1) {
            g2 = __uint_as_float(*(const unsigned*)(emsg + (size_t)ke * 16 + 10));
        } else {
            ksu = sue[ke];
            g2 = t2[ksu];
        }
        float p = t1[kidx] + g2;
        p = (p > 0.f) ? p : 0.2f * p;      // leaky_relu(0.2)
        lg = (kidx == 0) ? NEG_INF_F : p;  // pad mask
    }

    // Prefetch all value-phase rows (addresses don't depend on softmax).
    float wn[K_NB];
    float wm[K_NB];   // ITER1: bf16 feature element; ITER2: WhWm row element
#pragma unroll
    for (int k = 0; k < K_NB; ++k) {
        int idx = readlane_i(kidx, k);
        wn[k] = bf2f(WGh16[(size_t)idx * H + lane]);
    }
#pragma unroll
    for (int k = 0; k < K_NB; ++k) {
        if (ITER == 1) {
            int e = readlane_i(ke, k);
            wm[k] = (lane < ADIM) ? bf2f(emsg[(size_t)e * 16 + lane]) : 0.f;
        } else {
            int sk = readlane_i(ksu, k);
            wm[k] = bf2f(WhWm16[(size_t)sk * H + lane]);
        }
    }

    // softmax across the 16-lane group
    float m = lg;
#pragma unroll
    for (int o = 8; o > 0; o >>= 1) m = fmaxf(m, __shfl_xor(m, o, 64));
    float ex = __expf(lg - m);
    float s = ex;
#pragma unroll
    for (int o = 8; o > 0; o >>= 1) s += __shfl_xor(s, o, 64);
    float alpha = ex / s;

    float acc = 0.f;
    float fr = 0.f;
#pragma unroll
    for (int k = 0; k < K_NB; ++k) {
        float ak = readlane_f(alpha, k);
        if (ITER == 1) {
            acc += ak * wn[k];
            fr  += ak * wm[k];
        } else {
            acc += ak * (wn[k] + wm[k]);
        }
    }
    if (ITER == 1) {
        float wmacc = c2[lane];
#pragma unroll
        for (int j = 0; j < ADIM; ++j)
            wmacc += readlane_f(fr, j) * W2[j * H + lane];
        acc += wmacc;
    }
    float o = (acc > 0.f) ? acc : expm1f(acc);   // elu
    hp_out[(size_t)(n + 1) * H + lane] = o;
}

// ---------------------------------------------------------------------------
// WGh2 = hp2@W_gat (bf16, t1 = f32 row.a1), WhWm2 = hp2@Wm_gat (bf16, t2)
// ---------------------------------------------------------------------------
__global__ __launch_bounds__(256) void k_gemm2(
    const float* __restrict__ hp,
    const float* __restrict__ W_gat, const float* __restrict__ Wm_gat,
    const float* __restrict__ a_gat,
    unsigned short* __restrict__ WGh16, unsigned short* __restrict__ WhWm16,
    float* __restrict__ t1, float* __restrict__ t2)
{
    int lane = threadIdx.x & 63;
    float wg[H], wm[H];
#pragma unroll
    for (int j = 0; j < H; ++j) {
        wg[j] = W_gat[j * H + lane];
        wm[j] = Wm_gat[j * H + lane];
    }
    float a1 = a_gat[lane], a2 = a_gat[H + lane];
    int row = blockIdx.x * 4 + (threadIdx.x >> 6);
    int stride = gridDim.x * 4;
    for (; row <= N_NODES; row += stride) {
        float hv = hp[(size_t)row * H + lane];
        float a = 0.f, b = 0.f;
#pragma unroll
        for (int j = 0; j < H; ++j) {
            float hj = readlane_f(hv, j);
            a += hj * wg[j];
            b += hj * wm[j];
        }
        WGh16[(size_t)row * H + lane]  = f2bf(a);
        WhWm16[(size_t)row * H + lane] = f2bf(b);
        float ta = a * a1, tb = b * a2;
#pragma unroll
        for (int o = 32; o > 0; o >>= 1) {
            ta += __shfl_xor(ta, o, 64);
            tb += __shfl_xor(tb, o, 64);
        }
        if (lane == 0) { t1[row] = ta; t2[row] = tb; }
    }
}

// ---------------------------------------------------------------------------
// out[b] = sum_m hp[l_scope[b,m]] — all 48 gathers prefetched (1 wave/SIMD,
// no TLP to hide latency otherwise).
// ---------------------------------------------------------------------------
__global__ __launch_bounds__(256) void k_out(
    const int* __restrict__ l_scope, const float* __restrict__ hp,
    float* __restrict__ out)
{
    int wave = threadIdx.x >> 6;
    int lane = threadIdx.x & 63;
    int b = blockIdx.x * 4 + wave;
    if (b >= B_MOL) return;
    int idx48 = (lane < MAXM_M) ? l_scope[b * MAXM_M + lane] : 0;
    float v[MAXM_M];
#pragma unroll
    for (int m = 0; m < MAXM_M; ++m) {
        int idx = readlane_i(idx48, m);
        v[m] = hp[(size_t)idx * H + lane];
    }
    float acc = 0.f;
#pragma unroll
    for (int m = 0; m < MAXM_M; ++m) acc += v[m];
    out[b * H + lane] = acc;
}

extern "C" void kernel_launch(void* const* d_in, const int* in_sizes, int n_in,
                              void* d_out, int out_size, void* d_ws, size_t ws_size,
                              hipStream_t stream)
{
    const float* tf     = (const float*)d_in[0];
    const float* fdg    = (const float*)d_in[1];
    const float* rij    = (const float*)d_in[2];
    const int*   sse    = (const int*)d_in[3];
    const int*   bsc    = (const int*)d_in[4];
    const int*   lsc    = (const int*)d_in[5];
    const int*   su     = (const int*)d_in[6];
    const int*   sul    = (const int*)d_in[7];
    const float* W_emb  = (const float*)d_in[8];
    const float* b_emb  = (const float*)d_in[9];
    const float* W_dist = (const float*)d_in[10];
    const float* b_dist = (const float*)d_in[11];
    const float* W_gat  = (const float*)d_in[12];
    const float* Wm_gat = (const float*)d_in[13];
    const float* a_gat  = (const float*)d_in[14];
    float* out = (float*)d_out;

    char* base = (char*)d_ws;
    size_t off = 0;
    auto alloc = [&](size_t bytes) {
        char* p = base + off;
        off = (off + bytes + 255) & ~(size_t)255;
        return p;
    };
    float* W2   = (float*)alloc(640 * 4);
    float* c2   = (float*)alloc(64 * 4);
    float* W3   = (float*)alloc(576 * 4);
    float* c3   = (float*)alloc(64 * 4);
    float* wa   = (float*)alloc(16 * 4);
    float* ca   = (float*)alloc(16 * 4);
    float* t1   = (float*)alloc((size_t)(N_NODES + 1) * 4);
    float* t2   = (float*)alloc((size_t)(N_NODES + 1) * 4);
    int*   sue  = (int*)alloc((size_t)E_EDGES * 4);
    unsigned short* WGh16  = (unsigned short*)alloc((size_t)(N_NODES + 1) * H * 2);
    unsigned short* WhWm16 = (unsigned short*)alloc((size_t)(N_NODES + 1) * H * 2);
    float* hp2  = (float*)alloc((size_t)(N_NODES + 1) * H * 4);
    // emsg (25.6MB) and hp3 (12.8MB) alias: emsg dead before k_gat<2> writes hp3
    char*  big  = alloc((size_t)E_EDGES * 32);
    unsigned short* emsg = (unsigned short*)big;
    float* hp3  = (float*)big;

    k_fold<<<dim3(6), dim3(256), 0, stream>>>(W_emb, b_emb, W_dist, b_dist,
                                              W_gat, Wm_gat, a_gat,
                                              W2, c2, W3, c3, wa, ca);

    k_pre<<<dim3(NODE_BLOCKS + EDGE_BLOCKS), dim3(256), 0, stream>>>(
        tf, fdg, rij, su, sul, W3, c3, wa, ca, a_gat, WGh16, t1, emsg, sue);

    dim3 gat_grid((N_NODES + 3) / 4);
    k_gat<1><<<gat_grid, dim3(256), 0, stream>>>(
        sse, bsc, WGh16, t1, emsg, W2, c2, sue, t2, WhWm16, hp2);

    k_gemm2<<<dim3(1024), dim3(256), 0, stream>>>(
        hp2, W_gat, Wm_gat, a_gat, WGh16, WhWm16, t1, t2);

    k_gat<2><<<gat_grid, dim3(256), 0, stream>>>(
        sse, bsc, WGh16, t1, emsg, W2, c2, sue, t2, WhWm16, hp3);

    k_out<<<dim3(B_MOL / 4), dim3(256), 0, stream>>>(lsc, hp3, out);
}

// Round 5
// 252.627 us; speedup vs baseline: 2.1859x; 1.0091x over previous
//
#include <hip/hip_runtime.h>
#include <hip/hip_bf16.h>

#define N_NODES 50000
#define K_NB 16
#define E_EDGES 800000
#define B_MOL 1024
#define MAXM_M 48
#define FDIM 9
#define ADIM 10
#define H 64
#define NEG_INF_F (-1e9f)
#define NODE_BLOCKS 12500   /* 4 nodes per 256-thread block */
#define EDGE_BLOCKS 3125    /* 256 edges per block */

__device__ inline float readlane_f(float v, int l) {
    return __int_as_float(__builtin_amdgcn_readlane(__float_as_int(v), l));
}
__device__ inline int readlane_i(int v, int l) {
    return __builtin_amdgcn_readlane(v, l);
}
__device__ inline float bf2f(unsigned short u) {
    return __uint_as_float(((unsigned)u) << 16);
}
__device__ inline unsigned short f2bf(float f) {   // round-to-nearest-even
    unsigned x = __float_as_uint(f);
    return (unsigned short)((x + 0x7fffu + ((x >> 16) & 1u)) >> 16);
}

// ---------------------------------------------------------------------------
// Fold weights:
//   W2[10,64] = W_dist @ Wm_gat     c2[64] = b_dist @ Wm_gat
//   W3[9,64]  = W_emb  @ W_gat      c3[64] = b_emb  @ W_gat
//   wa[10]    = W_dist @ (Wm_gat @ a2)      ca = b_dist . (Wm_gat @ a2)
// ---------------------------------------------------------------------------
__global__ __launch_bounds__(256) void k_fold(
    const float* __restrict__ W_emb, const float* __restrict__ b_emb,
    const float* __restrict__ W_dist, const float* __restrict__ b_dist,
    const float* __restrict__ W_gat, const float* __restrict__ Wm_gat,
    const float* __restrict__ a_gat,
    float* __restrict__ W2, float* __restrict__ c2,
    float* __restrict__ W3, float* __restrict__ c3,
    float* __restrict__ wa, float* __restrict__ ca)
{
    int tid = blockIdx.x * 256 + threadIdx.x;
    if (tid < 640) {                       // W2
        int j = tid >> 6, h = tid & 63;
        float acc = 0.f;
        for (int t = 0; t < H; ++t) acc += W_dist[j * H + t] * Wm_gat[t * H + h];
        W2[tid] = acc;
    } else if (tid < 704) {                // c2
        int h = tid - 640;
        float acc = 0.f;
        for (int t = 0; t < H; ++t) acc += b_dist[t] * Wm_gat[t * H + h];
        c2[h] = acc;
    } else if (tid < 1280) {               // W3
        int q = tid - 704, j = q >> 6, h = q & 63;
        float acc = 0.f;
        for (int t = 0; t < H; ++t) acc += W_emb[j * H + t] * W_gat[t * H + h];
        W3[q] = acc;
    } else if (tid < 1344) {               // c3
        int h = tid - 1280;
        float acc = 0.f;
        for (int t = 0; t < H; ++t) acc += b_emb[t] * W_gat[t * H + h];
        c3[h] = acc;
    } else if (tid < 1408) {               // special wave: wa, ca
        int lane = tid - 1344;
        float v = 0.f;                     // v[lane] = Wm_gat[lane,:] . a2
        for (int h = 0; h < H; ++h) v += Wm_gat[lane * H + h] * a_gat[H + h];
        float acc = 0.f;
        for (int t = 0; t < H; ++t) {
            float vt = readlane_f(v, t);
            if (lane < ADIM)       acc += W_dist[lane * H + t] * vt;
            else if (lane == ADIM) acc += b_dist[t] * vt;
        }
        if (lane < ADIM)       wa[lane] = acc;
        else if (lane == ADIM) ca[0] = acc;
    }
}

// ---------------------------------------------------------------------------
// Fused pre-pass.
// Node section: WGh1 row n+1 = tf[n]@W3 + c3 (stored bf16), t1[row]=row.a1
// Edge section: pack emsg[e] (32B): ushort[0..9]=bf16(f0..f8,rij),
//               float elog at byte 20; and sue[e] = sul>0 ? su : 0
// ---------------------------------------------------------------------------
__global__ __launch_bounds__(256) void k_pre(
    const float* __restrict__ tf, const float* __restrict__ fdg,
    const float* __restrict__ rij,
    const int* __restrict__ su, const int* __restrict__ sul,
    const float* __restrict__ W3, const float* __restrict__ c3,
    const float* __restrict__ wa, const float* __restrict__ ca,
    const float* __restrict__ a_gat,
    unsigned short* __restrict__ WGh16, float* __restrict__ t1,
    unsigned short* __restrict__ emsg, int* __restrict__ sue)
{
    int bid = blockIdx.x;
    if (bid < NODE_BLOCKS) {
        int tid = bid * 256 + threadIdx.x;
        int n = tid >> 6, h = tid & 63;
        if (tid < 64) { WGh16[tid] = 0; if (tid == 0) t1[0] = 0.f; }
        float acc = c3[h];
#pragma unroll
        for (int j = 0; j < FDIM; ++j) acc += tf[n * FDIM + j] * W3[j * H + h];
        WGh16[(size_t)(n + 1) * H + h] = f2bf(acc);
        float tv = acc * a_gat[h];
#pragma unroll
        for (int o = 32; o > 0; o >>= 1) tv += __shfl_xor(tv, o, 64);
        if (h == 0) t1[n + 1] = tv;
    } else {
        int e = (bid - NODE_BLOCKS) * 256 + threadIdx.x;
        float f[ADIM];
#pragma unroll
        for (int j = 0; j < FDIM; ++j) f[j] = fdg[(size_t)e * FDIM + j];
        f[FDIM] = rij[e];
        float acc = ca[0];
#pragma unroll
        for (int j = 0; j < ADIM; ++j) acc += f[j] * wa[j];
        unsigned rec[8];
#pragma unroll
        for (int j = 0; j < 5; ++j)
            rec[j] = (unsigned)f2bf(f[2 * j]) | ((unsigned)f2bf(f[2 * j + 1]) << 16);
        rec[5] = __float_as_uint(acc);
        rec[6] = 0; rec[7] = 0;
        uint4* dst = (uint4*)(emsg + (size_t)e * 16);
        dst[0] = make_uint4(rec[0], rec[1], rec[2], rec[3]);
        dst[1] = make_uint4(rec[4], rec[5], rec[6], rec[7]);
        sue[e] = (sul[e] > 0) ? su[e] : 0;
    }
}

// ---------------------------------------------------------------------------
// GAT iteration, one wave per node, lane = feature.
// Round-5: sched_barrier(0) pins all 32 value-phase gathers before the
// softmax/consume code — round 4 showed the scheduler re-sinking them into
// the accumulate loop (VGPR_Count=28 -> serialized ~500cyc chains).
// ---------------------------------------------------------------------------
template <int ITER>
__global__ __launch_bounds__(256) void k_gat(
    const int* __restrict__ sse, const int* __restrict__ bsc,
    const unsigned short* __restrict__ WGh16, const float* __restrict__ t1,
    const unsigned short* __restrict__ emsg,
    const float* __restrict__ W2, const float* __restrict__ c2,
    const int* __restrict__ sue, const float* __restrict__ t2,
    const unsigned short* __restrict__ WhWm16,
    float* __restrict__ hp_out)
{
    int wave = threadIdx.x >> 6;
    int lane = threadIdx.x & 63;
    int n = blockIdx.x * 4 + wave;
    if (n == 0) hp_out[lane] = 0.f;        // zero pad row of output
    if (n >= N_NODES) return;

    // lanes 0..15 own neighbor k = lane
    int kidx = 0, ke = 0, ksu = 0;
    float lg = NEG_INF_F;
    if (lane < K_NB) {
        kidx = sse[n * K_NB + lane];
        ke   = bsc[n * K_NB + lane];
        float g2;
        if (ITER == 1) {
            g2 = __uint_as_float(*(const unsigned*)(emsg + (size_t)ke * 16 + 10));
        } else {
            ksu = sue[ke];
            g2 = t2[ksu];
        }
        float p = t1[kidx] + g2;
        p = (p > 0.f) ? p : 0.2f * p;      // leaky_relu(0.2)
        lg = (kidx == 0) ? NEG_INF_F : p;  // pad mask
    }

    // Prefetch all value-phase rows (addresses don't depend on softmax).
    float wn[K_NB];
    float wm[K_NB];   // ITER1: bf16 feature element; ITER2: WhWm row element
#pragma unroll
    for (int k = 0; k < K_NB; ++k) {
        int idx = readlane_i(kidx, k);
        wn[k] = bf2f(WGh16[(size_t)idx * H + lane]);
    }
#pragma unroll
    for (int k = 0; k < K_NB; ++k) {
        if (ITER == 1) {
            int e = readlane_i(ke, k);
            wm[k] = (lane < ADIM) ? bf2f(emsg[(size_t)e * 16 + lane]) : 0.f;
        } else {
            int sk = readlane_i(ksu, k);
            wm[k] = bf2f(WhWm16[(size_t)sk * H + lane]);
        }
    }
    // Nothing (especially the gathers above) may cross this point.
    __builtin_amdgcn_sched_barrier(0);

    // softmax across the 16-lane group
    float m = lg;
#pragma unroll
    for (int o = 8; o > 0; o >>= 1) m = fmaxf(m, __shfl_xor(m, o, 64));
    float ex = __expf(lg - m);
    float s = ex;
#pragma unroll
    for (int o = 8; o > 0; o >>= 1) s += __shfl_xor(s, o, 64);
    float alpha = ex / s;

    float acc = 0.f;
    float fr = 0.f;
#pragma unroll
    for (int k = 0; k < K_NB; ++k) {
        float ak = readlane_f(alpha, k);
        if (ITER == 1) {
            acc += ak * wn[k];
            fr  += ak * wm[k];
        } else {
            acc += ak * (wn[k] + wm[k]);
        }
    }
    if (ITER == 1) {
        float wmacc = c2[lane];
#pragma unroll
        for (int j = 0; j < ADIM; ++j)
            wmacc += readlane_f(fr, j) * W2[j * H + lane];
        acc += wmacc;
    }
    float o = (acc > 0.f) ? acc : expm1f(acc);   // elu
    hp_out[(size_t)(n + 1) * H + lane] = o;
}

// ---------------------------------------------------------------------------
// WGh2 = hp2@W_gat (bf16, t1 = f32 row.a1), WhWm2 = hp2@Wm_gat (bf16, t2)
// ---------------------------------------------------------------------------
__global__ __launch_bounds__(256) void k_gemm2(
    const float* __restrict__ hp,
    const float* __restrict__ W_gat, const float* __restrict__ Wm_gat,
    const float* __restrict__ a_gat,
    unsigned short* __restrict__ WGh16, unsigned short* __restrict__ WhWm16,
    float* __restrict__ t1, float* __restrict__ t2)
{
    int lane = threadIdx.x & 63;
    float wg[H], wm[H];
#pragma unroll
    for (int j = 0; j < H; ++j) {
        wg[j] = W_gat[j * H + lane];
        wm[j] = Wm_gat[j * H + lane];
    }
    float a1 = a_gat[lane], a2 = a_gat[H + lane];
    int row = blockIdx.x * 4 + (threadIdx.x >> 6);
    int stride = gridDim.x * 4;
    for (; row <= N_NODES; row += stride) {
        float hv = hp[(size_t)row * H + lane];
        float a = 0.f, b = 0.f;
#pragma unroll
        for (int j = 0; j < H; ++j) {
            float hj = readlane_f(hv, j);
            a += hj * wg[j];
            b += hj * wm[j];
        }
        WGh16[(size_t)row * H + lane]  = f2bf(a);
        WhWm16[(size_t)row * H + lane] = f2bf(b);
        float ta = a * a1, tb = b * a2;
#pragma unroll
        for (int o = 32; o > 0; o >>= 1) {
            ta += __shfl_xor(ta, o, 64);
            tb += __shfl_xor(tb, o, 64);
        }
        if (lane == 0) { t1[row] = ta; t2[row] = tb; }
    }
}

// ---------------------------------------------------------------------------
// out[b] = sum_m hp[l_scope[b,m]] — all 48 gathers pinned in flight.
// ---------------------------------------------------------------------------
__global__ __launch_bounds__(256) void k_out(
    const int* __restrict__ l_scope, const float* __restrict__ hp,
    float* __restrict__ out)
{
    int wave = threadIdx.x >> 6;
    int lane = threadIdx.x & 63;
    int b = blockIdx.x * 4 + wave;
    if (b >= B_MOL) return;
    int idx48 = (lane < MAXM_M) ? l_scope[b * MAXM_M + lane] : 0;
    float v[MAXM_M];
#pragma unroll
    for (int m = 0; m < MAXM_M; ++m) {
        int idx = readlane_i(idx48, m);
        v[m] = hp[(size_t)idx * H + lane];
    }
    __builtin_amdgcn_sched_barrier(0);
    float acc = 0.f;
#pragma unroll
    for (int m = 0; m < MAXM_M; ++m) acc += v[m];
    out[b * H + lane] = acc;
}

extern "C" void kernel_launch(void* const* d_in, const int* in_sizes, int n_in,
                              void* d_out, int out_size, void* d_ws, size_t ws_size,
                              hipStream_t stream)
{
    const float* tf     = (const float*)d_in[0];
    const float* fdg    = (const float*)d_in[1];
    const float* rij    = (const float*)d_in[2];
    const int*   sse    = (const int*)d_in[3];
    const int*   bsc    = (const int*)d_in[4];
    const int*   lsc    = (const int*)d_in[5];
    const int*   su     = (const int*)d_in[6];
    const int*   sul    = (const int*)d_in[7];
    const float* W_emb  = (const float*)d_in[8];
    const float* b_emb  = (const float*)d_in[9];
    const float* W_dist = (const float*)d_in[10];
    const float* b_dist = (const float*)d_in[11];
    const float* W_gat  = (const float*)d_in[12];
    const float* Wm_gat = (const float*)d_in[13];
    const float* a_gat  = (const float*)d_in[14];
    float* out = (float*)d_out;

    char* base = (char*)d_ws;
    size_t off = 0;
    auto alloc = [&](size_t bytes) {
        char* p = base + off;
        off = (off + bytes + 255) & ~(size_t)255;
        return p;
    };
    float* W2   = (float*)alloc(640 * 4);
    float* c2   = (float*)alloc(64 * 4);
    float* W3   = (float*)alloc(576 * 4);
    float* c3   = (float*)alloc(64 * 4);
    float* wa   = (float*)alloc(16 * 4);
    float* ca   = (float*)alloc(16 * 4);
    float* t1   = (float*)alloc((size_t)(N_NODES + 1) * 4);
    float* t2   = (float*)alloc((size_t)(N_NODES + 1) * 4);
    int*   sue  = (int*)alloc((size_t)E_EDGES * 4);
    unsigned short* WGh16  = (unsigned short*)alloc((size_t)(N_NODES + 1) * H * 2);
    unsigned short* WhWm16 = (unsigned short*)alloc((size_t)(N_NODES + 1) * H * 2);
    float* hp2  = (float*)alloc((size_t)(N_NODES + 1) * H * 4);
    // emsg (25.6MB) and hp3 (12.8MB) alias: emsg dead before k_gat<2> writes hp3
    char*  big  = alloc((size_t)E_EDGES * 32);
    unsigned short* emsg = (unsigned short*)big;
    float* hp3  = (float*)big;

    k_fold<<<dim3(6), dim3(256), 0, stream>>>(W_emb, b_emb, W_dist, b_dist,
                                              W_gat, Wm_gat, a_gat,
                                              W2, c2, W3, c3, wa, ca);

    k_pre<<<dim3(NODE_BLOCKS + EDGE_BLOCKS), dim3(256), 0, stream>>>(
        tf, fdg, rij, su, sul, W3, c3, wa, ca, a_gat, WGh16, t1, emsg, sue);

    dim3 gat_grid((N_NODES + 3) / 4);
    k_gat<1><<<gat_grid, dim3(256), 0, stream>>>(
        sse, bsc, WGh16, t1, emsg, W2, c2, sue, t2, WhWm16, hp2);

    k_gemm2<<<dim3(1024), dim3(256), 0, stream>>>(
        hp2, W_gat, Wm_gat, a_gat, WGh16, WhWm16, t1, t2);

    k_gat<2><<<gat_grid, dim3(256), 0, stream>>>(
        sse, bsc, WGh16, t1, emsg, W2, c2, sue, t2, WhWm16, hp3);

    k_out<<<dim3(B_MOL / 4), dim3(256), 0, stream>>>(lsc, hp3, out);
}

// Round 6
// 234.161 us; speedup vs baseline: 2.3583x; 1.0789x over previous
//
#include <hip/hip_runtime.h>
#include <hip/hip_bf16.h>

#define N_NODES 50000
#define K_NB 16
#define E_EDGES 800000
#define B_MOL 1024
#define MAXM_M 48
#define FDIM 9
#define ADIM 10
#define H 64
#define NEG_INF_F (-1e9f)
#define NODE_BLOCKS 12500   /* 4 nodes per 256-thread block */
#define EDGE_BLOCKS 3125    /* 256 edges per block */

__device__ inline float readlane_f(float v, int l) {
    return __int_as_float(__builtin_amdgcn_readlane(__float_as_int(v), l));
}
__device__ inline int readlane_i(int v, int l) {
    return __builtin_amdgcn_readlane(v, l);
}
__device__ inline float bf2f(unsigned u) {         // u = zero-extended bf16
    return __uint_as_float(u << 16);
}
__device__ inline unsigned short f2bf(float f) {   // round-to-nearest-even
    unsigned x = __float_as_uint(f);
    return (unsigned short)((x + 0x7fffu + ((x >> 16) & 1u)) >> 16);
}

// Raw gather: dst <- mem[sbase + voff]. SGPR base (wave-uniform row) +
// per-lane VGPR byte offset. Issued exactly where written; result NOT ready
// until the manual s_waitcnt drain below (values are threaded through it).
#define GLOAD_U16(dst, voff, sbase) \
    asm volatile("global_load_ushort %0, %1, %2" : "=v"(dst) : "v"(voff), "s"(sbase))
#define GLOAD_F32(dst, voff, sbase) \
    asm volatile("global_load_dword %0, %1, %2" : "=v"(dst) : "v"(voff), "s"(sbase))

// ---------------------------------------------------------------------------
// Fold weights:
//   W2[10,64] = W_dist @ Wm_gat     c2[64] = b_dist @ Wm_gat
//   W3[9,64]  = W_emb  @ W_gat      c3[64] = b_emb  @ W_gat
//   wa[10]    = W_dist @ (Wm_gat @ a2)      ca = b_dist . (Wm_gat @ a2)
// ---------------------------------------------------------------------------
__global__ __launch_bounds__(256) void k_fold(
    const float* __restrict__ W_emb, const float* __restrict__ b_emb,
    const float* __restrict__ W_dist, const float* __restrict__ b_dist,
    const float* __restrict__ W_gat, const float* __restrict__ Wm_gat,
    const float* __restrict__ a_gat,
    float* __restrict__ W2, float* __restrict__ c2,
    float* __restrict__ W3, float* __restrict__ c3,
    float* __restrict__ wa, float* __restrict__ ca)
{
    int tid = blockIdx.x * 256 + threadIdx.x;
    if (tid < 640) {                       // W2
        int j = tid >> 6, h = tid & 63;
        float acc = 0.f;
        for (int t = 0; t < H; ++t) acc += W_dist[j * H + t] * Wm_gat[t * H + h];
        W2[tid] = acc;
    } else if (tid < 704) {                // c2
        int h = tid - 640;
        float acc = 0.f;
        for (int t = 0; t < H; ++t) acc += b_dist[t] * Wm_gat[t * H + h];
        c2[h] = acc;
    } else if (tid < 1280) {               // W3
        int q = tid - 704, j = q >> 6, h = q & 63;
        float acc = 0.f;
        for (int t = 0; t < H; ++t) acc += W_emb[j * H + t] * W_gat[t * H + h];
        W3[q] = acc;
    } else if (tid < 1344) {               // c3
        int h = tid - 1280;
        float acc = 0.f;
        for (int t = 0; t < H; ++t) acc += b_emb[t] * W_gat[t * H + h];
        c3[h] = acc;
    } else if (tid < 1408) {               // special wave: wa, ca
        int lane = tid - 1344;
        float v = 0.f;                     // v[lane] = Wm_gat[lane,:] . a2
        for (int h = 0; h < H; ++h) v += Wm_gat[lane * H + h] * a_gat[H + h];
        float acc = 0.f;
        for (int t = 0; t < H; ++t) {
            float vt = readlane_f(v, t);
            if (lane < ADIM)       acc += W_dist[lane * H + t] * vt;
            else if (lane == ADIM) acc += b_dist[t] * vt;
        }
        if (lane < ADIM)       wa[lane] = acc;
        else if (lane == ADIM) ca[0] = acc;
    }
}

// ---------------------------------------------------------------------------
// Fused pre-pass.
// Node section: WGh1 row n+1 = tf[n]@W3 + c3 (stored bf16), t1[row]=row.a1
// Edge section: pack emsg[e] (32B): ushort[0..9]=bf16(f0..f8,rij),
//               float elog at byte 20; and sue[e] = sul>0 ? su : 0
// ---------------------------------------------------------------------------
__global__ __launch_bounds__(256) void k_pre(
    const float* __restrict__ tf, const float* __restrict__ fdg,
    const float* __restrict__ rij,
    const int* __restrict__ su, const int* __restrict__ sul,
    const float* __restrict__ W3, const float* __restrict__ c3,
    const float* __restrict__ wa, const float* __restrict__ ca,
    const float* __restrict__ a_gat,
    unsigned short* __restrict__ WGh16, float* __restrict__ t1,
    unsigned short* __restrict__ emsg, int* __restrict__ sue)
{
    int bid = blockIdx.x;
    if (bid < NODE_BLOCKS) {
        int tid = bid * 256 + threadIdx.x;
        int n = tid >> 6, h = tid & 63;
        if (tid < 64) { WGh16[tid] = 0; if (tid == 0) t1[0] = 0.f; }
        float acc = c3[h];
#pragma unroll
        for (int j = 0; j < FDIM; ++j) acc += tf[n * FDIM + j] * W3[j * H + h];
        WGh16[(size_t)(n + 1) * H + h] = f2bf(acc);
        float tv = acc * a_gat[h];
#pragma unroll
        for (int o = 32; o > 0; o >>= 1) tv += __shfl_xor(tv, o, 64);
        if (h == 0) t1[n + 1] = tv;
    } else {
        int e = (bid - NODE_BLOCKS) * 256 + threadIdx.x;
        float f[ADIM];
#pragma unroll
        for (int j = 0; j < FDIM; ++j) f[j] = fdg[(size_t)e * FDIM + j];
        f[FDIM] = rij[e];
        float acc = ca[0];
#pragma unroll
        for (int j = 0; j < ADIM; ++j) acc += f[j] * wa[j];
        unsigned rec[8];
#pragma unroll
        for (int j = 0; j < 5; ++j)
            rec[j] = (unsigned)f2bf(f[2 * j]) | ((unsigned)f2bf(f[2 * j + 1]) << 16);
        rec[5] = __float_as_uint(acc);
        rec[6] = 0; rec[7] = 0;
        uint4* dst = (uint4*)(emsg + (size_t)e * 16);
        dst[0] = make_uint4(rec[0], rec[1], rec[2], rec[3]);
        dst[1] = make_uint4(rec[4], rec[5], rec[6], rec[7]);
        sue[e] = (sul[e] > 0) ? su[e] : 0;
    }
}

// ---------------------------------------------------------------------------
// GAT iteration, one wave per node, lane = feature.
// Round-6: the 32 value-phase row gathers are raw inline-asm loads with
// wave-uniform SGPR bases — compiler cannot sink/serialize them. One manual
// vmcnt(0) drain; consume code data-threaded through it via "+v" operands.
// ---------------------------------------------------------------------------
template <int ITER>
__global__ __launch_bounds__(256) void k_gat(
    const int* __restrict__ sse, const int* __restrict__ bsc,
    const unsigned short* __restrict__ WGh16, const float* __restrict__ t1,
    const unsigned short* __restrict__ emsg,
    const float* __restrict__ W2, const float* __restrict__ c2,
    const int* __restrict__ sue, const float* __restrict__ t2,
    const unsigned short* __restrict__ WhWm16,
    float* __restrict__ hp_out)
{
    int wave = threadIdx.x >> 6;
    int lane = threadIdx.x & 63;
    int n = blockIdx.x * 4 + wave;
    if (n == 0) hp_out[lane] = 0.f;        // zero pad row of output
    if (n >= N_NODES) return;

    // lanes 0..15 own neighbor k = lane (logit phase)
    int kidx = 0, ke = 0, ksu = 0;
    float lg = NEG_INF_F;
    if (lane < K_NB) {
        kidx = sse[n * K_NB + lane];
        ke   = bsc[n * K_NB + lane];
        float g2;
        if (ITER == 1) {
            g2 = __uint_as_float(*(const unsigned*)(emsg + (size_t)ke * 16 + 10));
        } else {
            ksu = sue[ke];
            g2 = t2[ksu];
        }
        float p = t1[kidx] + g2;
        p = (p > 0.f) ? p : 0.2f * p;      // leaky_relu(0.2)
        lg = (kidx == 0) ? NEG_INF_F : p;  // pad mask
    }

    // Issue all 32 row gathers (addresses independent of softmax).
    unsigned wn_u[K_NB], wm_u[K_NB];
    int off  = lane * 2;            // byte offset within a 128B bf16 row
    int offm = (lane & 15) * 2;     // byte offset within a 32B emsg record
#pragma unroll
    for (int k = 0; k < K_NB; ++k) {
        const unsigned short* pk = WGh16 + (size_t)readlane_i(kidx, k) * H;
        GLOAD_U16(wn_u[k], off, pk);
    }
#pragma unroll
    for (int k = 0; k < K_NB; ++k) {
        if (ITER == 1) {
            const unsigned short* pe = emsg + (size_t)readlane_i(ke, k) * 16;
            GLOAD_U16(wm_u[k], offm, pe);
        } else {
            const unsigned short* ps = WhWm16 + (size_t)readlane_i(ksu, k) * H;
            GLOAD_U16(wm_u[k], off, ps);
        }
    }

    // softmax across the 16-lane group — overlaps the gathers
    float m = lg;
#pragma unroll
    for (int o = 8; o > 0; o >>= 1) m = fmaxf(m, __shfl_xor(m, o, 64));
    float ex = __expf(lg - m);
    float s = ex;
#pragma unroll
    for (int o = 8; o > 0; o >>= 1) s += __shfl_xor(s, o, 64);
    float alpha = ex / s;

    // Drain: all consumes below depend on these asm outputs.
    asm volatile("s_waitcnt vmcnt(0)"
        : "+v"(wn_u[0]), "+v"(wn_u[1]), "+v"(wn_u[2]), "+v"(wn_u[3]),
          "+v"(wn_u[4]), "+v"(wn_u[5]), "+v"(wn_u[6]), "+v"(wn_u[7]),
          "+v"(wn_u[8]), "+v"(wn_u[9]), "+v"(wn_u[10]), "+v"(wn_u[11]),
          "+v"(wn_u[12]), "+v"(wn_u[13]), "+v"(wn_u[14]), "+v"(wn_u[15]));
    asm volatile(""
        : "+v"(wm_u[0]), "+v"(wm_u[1]), "+v"(wm_u[2]), "+v"(wm_u[3]),
          "+v"(wm_u[4]), "+v"(wm_u[5]), "+v"(wm_u[6]), "+v"(wm_u[7]),
          "+v"(wm_u[8]), "+v"(wm_u[9]), "+v"(wm_u[10]), "+v"(wm_u[11]),
          "+v"(wm_u[12]), "+v"(wm_u[13]), "+v"(wm_u[14]), "+v"(wm_u[15]));

    float acc = 0.f;
    float fr = 0.f;
#pragma unroll
    for (int k = 0; k < K_NB; ++k) {
        float ak = readlane_f(alpha, k);
        if (ITER == 1) {
            acc += ak * bf2f(wn_u[k]);
            fr  += ak * bf2f(wm_u[k]);     // lanes >= ADIM: garbage, never read
        } else {
            acc += ak * (bf2f(wn_u[k]) + bf2f(wm_u[k]));
        }
    }
    if (ITER == 1) {
        float wmacc = c2[lane];
#pragma unroll
        for (int j = 0; j < ADIM; ++j)
            wmacc += readlane_f(fr, j) * W2[j * H + lane];
        acc += wmacc;
    }
    float o = (acc > 0.f) ? acc : expm1f(acc);   // elu
    hp_out[(size_t)(n + 1) * H + lane] = o;
}

// ---------------------------------------------------------------------------
// WGh2 = hp2@W_gat (bf16, t1 = f32 row.a1), WhWm2 = hp2@Wm_gat (bf16, t2)
// ---------------------------------------------------------------------------
__global__ __launch_bounds__(256) void k_gemm2(
    const float* __restrict__ hp,
    const float* __restrict__ W_gat, const float* __restrict__ Wm_gat,
    const float* __restrict__ a_gat,
    unsigned short* __restrict__ WGh16, unsigned short* __restrict__ WhWm16,
    float* __restrict__ t1, float* __restrict__ t2)
{
    int lane = threadIdx.x & 63;
    float wg[H], wm[H];
#pragma unroll
    for (int j = 0; j < H; ++j) {
        wg[j] = W_gat[j * H + lane];
        wm[j] = Wm_gat[j * H + lane];
    }
    float a1 = a_gat[lane], a2 = a_gat[H + lane];
    int row = blockIdx.x * 4 + (threadIdx.x >> 6);
    int stride = gridDim.x * 4;
    for (; row <= N_NODES; row += stride) {
        float hv = hp[(size_t)row * H + lane];
        float a = 0.f, b = 0.f;
#pragma unroll
        for (int j = 0; j < H; ++j) {
            float hj = readlane_f(hv, j);
            a += hj * wg[j];
            b += hj * wm[j];
        }
        WGh16[(size_t)row * H + lane]  = f2bf(a);
        WhWm16[(size_t)row * H + lane] = f2bf(b);
        float ta = a * a1, tb = b * a2;
#pragma unroll
        for (int o = 32; o > 0; o >>= 1) {
            ta += __shfl_xor(ta, o, 64);
            tb += __shfl_xor(tb, o, 64);
        }
        if (lane == 0) { t1[row] = ta; t2[row] = tb; }
    }
}

// ---------------------------------------------------------------------------
// out[b] = sum_m hp[l_scope[b,m]] — 48 raw asm gathers all in flight
// (1 wave/SIMD here: no TLP, MLP is the only latency cover).
// ---------------------------------------------------------------------------
__global__ __launch_bounds__(256) void k_out(
    const int* __restrict__ l_scope, const float* __restrict__ hp,
    float* __restrict__ out)
{
    int wave = threadIdx.x >> 6;
    int lane = threadIdx.x & 63;
    int b = blockIdx.x * 4 + wave;
    if (b >= B_MOL) return;
    int idx48 = (lane < MAXM_M) ? l_scope[b * MAXM_M + lane] : 0;
    float v[MAXM_M];
    int off = lane * 4;
#pragma unroll
    for (int m = 0; m < MAXM_M; ++m) {
        const float* pm = hp + (size_t)readlane_i(idx48, m) * H;
        GLOAD_F32(v[m], off, pm);
    }
    asm volatile("s_waitcnt vmcnt(0)"
        : "+v"(v[0]), "+v"(v[1]), "+v"(v[2]), "+v"(v[3]),
          "+v"(v[4]), "+v"(v[5]), "+v"(v[6]), "+v"(v[7]),
          "+v"(v[8]), "+v"(v[9]), "+v"(v[10]), "+v"(v[11]),
          "+v"(v[12]), "+v"(v[13]), "+v"(v[14]), "+v"(v[15]));
    asm volatile(""
        : "+v"(v[16]), "+v"(v[17]), "+v"(v[18]), "+v"(v[19]),
          "+v"(v[20]), "+v"(v[21]), "+v"(v[22]), "+v"(v[23]),
          "+v"(v[24]), "+v"(v[25]), "+v"(v[26]), "+v"(v[27]),
          "+v"(v[28]), "+v"(v[29]), "+v"(v[30]), "+v"(v[31]));
    asm volatile(""
        : "+v"(v[32]), "+v"(v[33]), "+v"(v[34]), "+v"(v[35]),
          "+v"(v[36]), "+v"(v[37]), "+v"(v[38]), "+v"(v[39]),
          "+v"(v[40]), "+v"(v[41]), "+v"(v[42]), "+v"(v[43]),
          "+v"(v[44]), "+v"(v[45]), "+v"(v[46]), "+v"(v[47]));
    float acc = 0.f;
#pragma unroll
    for (int m = 0; m < MAXM_M; ++m) acc += v[m];
    out[b * H + lane] = acc;
}

extern "C" void kernel_launch(void* const* d_in, const int* in_sizes, int n_in,
                              void* d_out, int out_size, void* d_ws, size_t ws_size,
                              hipStream_t stream)
{
    const float* tf     = (const float*)d_in[0];
    const float* fdg    = (const float*)d_in[1];
    const float* rij    = (const float*)d_in[2];
    const int*   sse    = (const int*)d_in[3];
    const int*   bsc    = (const int*)d_in[4];
    const int*   lsc    = (const int*)d_in[5];
    const int*   su     = (const int*)d_in[6];
    const int*   sul    = (const int*)d_in[7];
    const float* W_emb  = (const float*)d_in[8];
    const float* b_emb  = (const float*)d_in[9];
    const float* W_dist = (const float*)d_in[10];
    const float* b_dist = (const float*)d_in[11];
    const float* W_gat  = (const float*)d_in[12];
    const float* Wm_gat = (const float*)d_in[13];
    const float* a_gat  = (const float*)d_in[14];
    float* out = (float*)d_out;

    char* base = (char*)d_ws;
    size_t off = 0;
    auto alloc = [&](size_t bytes) {
        char* p = base + off;
        off = (off + bytes + 255) & ~(size_t)255;
        return p;
    };
    float* W2   = (float*)alloc(640 * 4);
    float* c2   = (float*)alloc(64 * 4);
    float* W3   = (float*)alloc(576 * 4);
    float* c3   = (float*)alloc(64 * 4);
    float* wa   = (float*)alloc(16 * 4);
    float* ca   = (float*)alloc(16 * 4);
    float* t1   = (float*)alloc((size_t)(N_NODES + 1) * 4);
    float* t2   = (float*)alloc((size_t)(N_NODES + 1) * 4);
    int*   sue  = (int*)alloc((size_t)E_EDGES * 4);
    unsigned short* WGh16  = (unsigned short*)alloc((size_t)(N_NODES + 1) * H * 2);
    unsigned short* WhWm16 = (unsigned short*)alloc((size_t)(N_NODES + 1) * H * 2);
    float* hp2  = (float*)alloc((size_t)(N_NODES + 1) * H * 4);
    // emsg (25.6MB) and hp3 (12.8MB) alias: emsg dead before k_gat<2> writes hp3
    char*  big  = alloc((size_t)E_EDGES * 32);
    unsigned short* emsg = (unsigned short*)big;
    float* hp3  = (float*)big;

    k_fold<<<dim3(6), dim3(256), 0, stream>>>(W_emb, b_emb, W_dist, b_dist,
                                              W_gat, Wm_gat, a_gat,
                                              W2, c2, W3, c3, wa, ca);

    k_pre<<<dim3(NODE_BLOCKS + EDGE_BLOCKS), dim3(256), 0, stream>>>(
        tf, fdg, rij, su, sul, W3, c3, wa, ca, a_gat, WGh16, t1, emsg, sue);

    dim3 gat_grid((N_NODES + 3) / 4);
    k_gat<1><<<gat_grid, dim3(256), 0, stream>>>(
        sse, bsc, WGh16, t1, emsg, W2, c2, sue, t2, WhWm16, hp2);

    k_gemm2<<<dim3(1024), dim3(256), 0, stream>>>(
        hp2, W_gat, Wm_gat, a_gat, WGh16, WhWm16, t1, t2);

    k_gat<2><<<gat_grid, dim3(256), 0, stream>>>(
        sse, bsc, WGh16, t1, emsg, W2, c2, sue, t2, WhWm16, hp3);

    k_out<<<dim3(B_MOL / 4), dim3(256), 0, stream>>>(lsc, hp3, out);
}

// Round 7
// 232.951 us; speedup vs baseline: 2.3705x; 1.0052x over previous
//
#include <hip/hip_runtime.h>
#include <hip/hip_bf16.h>

#define N_NODES 50000
#define K_NB 16
#define E_EDGES 800000
#define B_MOL 1024
#define MAXM_M 48
#define FDIM 9
#define ADIM 10
#define H 64
#define NEG_INF_F (-1e9f)
#define PRE_NODE_BLOCKS 196  /* 1 thread per node */
#define EDGE_BLOCKS 3125     /* 256 edges per block */

__device__ inline float readlane_f(float v, int l) {
    return __int_as_float(__builtin_amdgcn_readlane(__float_as_int(v), l));
}
__device__ inline int readlane_i(int v, int l) {
    return __builtin_amdgcn_readlane(v, l);
}
__device__ inline float bf2f(unsigned u) {         // u = zero-extended bf16
    return __uint_as_float(u << 16);
}
__device__ inline unsigned short f2bf(float f) {   // round-to-nearest-even
    unsigned x = __float_as_uint(f);
    return (unsigned short)((x + 0x7fffu + ((x >> 16) & 1u)) >> 16);
}

// Raw gather with wave-uniform SGPR base + per-lane VGPR byte offset.
// Issued exactly where written; drained by the manual s_waitcnt below.
#define GLOAD_U16(dst, voff, sbase) \
    asm volatile("global_load_ushort %0, %1, %2" : "=v"(dst) : "v"(voff), "s"(sbase))
#define GLOAD_F32(dst, voff, sbase) \
    asm volatile("global_load_dword %0, %1, %2" : "=v"(dst) : "v"(voff), "s"(sbase))

#define DRAIN16(a) \
    asm volatile("s_waitcnt vmcnt(0)" \
        : "+v"(a[0]), "+v"(a[1]), "+v"(a[2]), "+v"(a[3]), \
          "+v"(a[4]), "+v"(a[5]), "+v"(a[6]), "+v"(a[7]), \
          "+v"(a[8]), "+v"(a[9]), "+v"(a[10]), "+v"(a[11]), \
          "+v"(a[12]), "+v"(a[13]), "+v"(a[14]), "+v"(a[15]))
#define HOLD16(a) \
    asm volatile("" \
        : "+v"(a[0]), "+v"(a[1]), "+v"(a[2]), "+v"(a[3]), \
          "+v"(a[4]), "+v"(a[5]), "+v"(a[6]), "+v"(a[7]), \
          "+v"(a[8]), "+v"(a[9]), "+v"(a[10]), "+v"(a[11]), \
          "+v"(a[12]), "+v"(a[13]), "+v"(a[14]), "+v"(a[15]))

// ---------------------------------------------------------------------------
// Fold all weight algebra (single block, LDS-staged):
//   va = W_gat@a1, vb = Wm_gat@a2
//   W2 = W_dist@Wm_gat, c2 = b_dist@Wm_gat
//   W3 = W_emb@W_gat,  c3 = b_emb@W_gat
//   wa = W_dist@vb, ca = b_dist.vb   (iter-1 edge logit)
//   wv9 = W_emb@va, cv = b_emb.va    (iter-1 node logit)
// ---------------------------------------------------------------------------
__global__ __launch_bounds__(256) void k_fold(
    const float* __restrict__ W_emb, const float* __restrict__ b_emb,
    const float* __restrict__ W_dist, const float* __restrict__ b_dist,
    const float* __restrict__ W_gat, const float* __restrict__ Wm_gat,
    const float* __restrict__ a_gat,
    float* __restrict__ W2, float* __restrict__ c2,
    float* __restrict__ W3, float* __restrict__ c3,
    float* __restrict__ wa, float* __restrict__ ca,
    float* __restrict__ va, float* __restrict__ vb,
    float* __restrict__ wv9, float* __restrict__ cv)
{
    __shared__ float s_va[64], s_vb[64];
    int tid = threadIdx.x;
    int h = tid & 63, g = tid >> 6;
    if (g == 0) {            // va[h] = W_gat[h,:] . a1
        float acc = 0.f;
        for (int t = 0; t < H; ++t) acc += W_gat[h * H + t] * a_gat[t];
        s_va[h] = acc; va[h] = acc;
    } else if (g == 1) {     // vb[h] = Wm_gat[h,:] . a2
        float acc = 0.f;
        for (int t = 0; t < H; ++t) acc += Wm_gat[h * H + t] * a_gat[H + t];
        s_vb[h] = acc; vb[h] = acc;
    } else if (g == 2) {     // c2
        float acc = 0.f;
        for (int t = 0; t < H; ++t) acc += b_dist[t] * Wm_gat[t * H + h];
        c2[h] = acc;
    } else {                 // c3
        float acc = 0.f;
        for (int t = 0; t < H; ++t) acc += b_emb[t] * W_gat[t * H + h];
        c3[h] = acc;
    }
    __syncthreads();
    for (int q = tid; q < 640; q += 256) {   // W2[j,h]
        int j = q >> 6, hh = q & 63;
        float acc = 0.f;
        for (int t = 0; t < H; ++t) acc += W_dist[j * H + t] * Wm_gat[t * H + hh];
        W2[q] = acc;
    }
    for (int q = tid; q < 576; q += 256) {   // W3[j,h]
        int j = q >> 6, hh = q & 63;
        float acc = 0.f;
        for (int t = 0; t < H; ++t) acc += W_emb[j * H + t] * W_gat[t * H + hh];
        W3[q] = acc;
    }
    if (tid < ADIM) {                         // wa
        float acc = 0.f;
        for (int t = 0; t < H; ++t) acc += W_dist[tid * H + t] * s_vb[t];
        wa[tid] = acc;
    } else if (tid == ADIM) {                 // ca
        float acc = 0.f;
        for (int t = 0; t < H; ++t) acc += b_dist[t] * s_vb[t];
        ca[0] = acc;
    } else if (tid >= 16 && tid < 16 + FDIM) {// wv9
        int j = tid - 16;
        float acc = 0.f;
        for (int t = 0; t < H; ++t) acc += W_emb[j * H + t] * s_va[t];
        wv9[j] = acc;
    } else if (tid == 31) {                   // cv
        float acc = 0.f;
        for (int t = 0; t < H; ++t) acc += b_emb[t] * s_va[t];
        cv[0] = acc;
    }
}

// ---------------------------------------------------------------------------
// Pre-pass.
// Node thread n: t1A[n+1] = tf[n].wv9 + cv; tfp record (32B, 16 bf16, 9 real).
// Edge thread e: emsg record (32B: 10 bf16 features, f32 elog at byte 20);
//               sue[e] = sul>0 ? su : 0.
// ---------------------------------------------------------------------------
__global__ __launch_bounds__(256) void k_pre(
    const float* __restrict__ tf, const float* __restrict__ fdg,
    const float* __restrict__ rij,
    const int* __restrict__ su, const int* __restrict__ sul,
    const float* __restrict__ wa, const float* __restrict__ ca,
    const float* __restrict__ wv9, const float* __restrict__ cv,
    float* __restrict__ t1A, unsigned short* __restrict__ tfp,
    unsigned short* __restrict__ emsg, int* __restrict__ sue)
{
    int bid = blockIdx.x;
    if (bid < PRE_NODE_BLOCKS) {
        int n = bid * 256 + threadIdx.x;
        if (n == 0) {                        // zero pad row
            t1A[0] = 0.f;
            uint4 z = make_uint4(0, 0, 0, 0);
            ((uint4*)tfp)[0] = z; ((uint4*)tfp)[1] = z;
        }
        if (n >= N_NODES) return;
        float f[FDIM];
        float acc = cv[0];
#pragma unroll
        for (int j = 0; j < FDIM; ++j) {
            f[j] = tf[n * FDIM + j];
            acc += f[j] * wv9[j];
        }
        t1A[n + 1] = acc;
        unsigned rec[8];
#pragma unroll
        for (int j = 0; j < 4; ++j)
            rec[j] = (unsigned)f2bf(f[2 * j]) | ((unsigned)f2bf(f[2 * j + 1]) << 16);
        rec[4] = (unsigned)f2bf(f[8]);
        rec[5] = 0; rec[6] = 0; rec[7] = 0;
        uint4* dst = (uint4*)(tfp + (size_t)(n + 1) * 16);
        dst[0] = make_uint4(rec[0], rec[1], rec[2], rec[3]);
        dst[1] = make_uint4(rec[4], rec[5], rec[6], rec[7]);
    } else {
        int e = (bid - PRE_NODE_BLOCKS) * 256 + threadIdx.x;
        float f[ADIM];
#pragma unroll
        for (int j = 0; j < FDIM; ++j) f[j] = fdg[(size_t)e * FDIM + j];
        f[FDIM] = rij[e];
        float acc = ca[0];
#pragma unroll
        for (int j = 0; j < ADIM; ++j) acc += f[j] * wa[j];
        unsigned rec[8];
#pragma unroll
        for (int j = 0; j < 5; ++j)
            rec[j] = (unsigned)f2bf(f[2 * j]) | ((unsigned)f2bf(f[2 * j + 1]) << 16);
        rec[5] = __float_as_uint(acc);
        rec[6] = 0; rec[7] = 0;
        uint4* dst = (uint4*)(emsg + (size_t)e * 16);
        dst[0] = make_uint4(rec[0], rec[1], rec[2], rec[3]);
        dst[1] = make_uint4(rec[4], rec[5], rec[6], rec[7]);
        sue[e] = (sul[e] > 0) ? su[e] : 0;
    }
}

// ---------------------------------------------------------------------------
// GAT iter 1. Gathers only the 9-dim tf table (1.6MB, L2-resident) and the
// 32B emsg records; projection (W3/W2) applied once per node. Epilogue
// emits hp2 row (bf16) + logit scalars t1B/t2B for iter 2 — no gemm pass.
// ---------------------------------------------------------------------------
__global__ __launch_bounds__(256) void k_gat1(
    const int* __restrict__ sse, const int* __restrict__ bsc,
    const float* __restrict__ t1A, const unsigned short* __restrict__ tfp,
    const unsigned short* __restrict__ emsg,
    const float* __restrict__ W2, const float* __restrict__ c2,
    const float* __restrict__ W3, const float* __restrict__ c3,
    const float* __restrict__ va, const float* __restrict__ vb,
    unsigned short* __restrict__ hp2bf, float* __restrict__ t1B,
    float* __restrict__ t2B)
{
    int wave = threadIdx.x >> 6;
    int lane = threadIdx.x & 63;
    int n = blockIdx.x * 4 + wave;
    if (n == 0) {
        hp2bf[lane] = 0;
        if (lane == 0) { t1B[0] = 0.f; t2B[0] = 0.f; }
    }
    if (n >= N_NODES) return;

    int kidx = 0, ke = 0;
    float lg = NEG_INF_F;
    if (lane < K_NB) {
        kidx = sse[n * K_NB + lane];
        ke   = bsc[n * K_NB + lane];
        float g2 = __uint_as_float(*(const unsigned*)(emsg + (size_t)ke * 16 + 10));
        float p = t1A[kidx] + g2;
        p = (p > 0.f) ? p : 0.2f * p;      // leaky_relu(0.2)
        lg = (kidx == 0) ? NEG_INF_F : p;  // pad mask
    }

    unsigned wn_u[K_NB], wm_u[K_NB];
    int offr = (lane & 15) * 2;            // short index within 32B record
#pragma unroll
    for (int k = 0; k < K_NB; ++k) {
        const unsigned short* pk = tfp + (size_t)readlane_i(kidx, k) * 16;
        GLOAD_U16(wn_u[k], offr, pk);
    }
#pragma unroll
    for (int k = 0; k < K_NB; ++k) {
        const unsigned short* pe = emsg + (size_t)readlane_i(ke, k) * 16;
        GLOAD_U16(wm_u[k], offr, pe);
    }

    // softmax across the 16-lane group — overlaps the gathers
    float m = lg;
#pragma unroll
    for (int o = 8; o > 0; o >>= 1) m = fmaxf(m, __shfl_xor(m, o, 64));
    float ex = __expf(lg - m);
    float s = ex;
#pragma unroll
    for (int o = 8; o > 0; o >>= 1) s += __shfl_xor(s, o, 64);
    float alpha = ex / s;

    DRAIN16(wn_u);
    HOLD16(wm_u);

    float fr = 0.f, frm = 0.f, beta = 0.f;
#pragma unroll
    for (int k = 0; k < K_NB; ++k) {
        float ak = readlane_f(alpha, k);
        fr  += ak * bf2f(wn_u[k]);         // lanes 9..15 read record pad zeros
        frm += ak * bf2f(wm_u[k]);         // lanes >= ADIM garbage, never read
        beta += (readlane_i(kidx, k) > 0) ? ak : 0.f;
    }
    float acc = c2[lane] + beta * c3[lane];
#pragma unroll
    for (int j = 0; j < FDIM; ++j) acc += readlane_f(fr, j) * W3[j * H + lane];
#pragma unroll
    for (int j = 0; j < ADIM; ++j) acc += readlane_f(frm, j) * W2[j * H + lane];
    float o = (acc > 0.f) ? acc : expm1f(acc);   // elu
    hp2bf[(size_t)(n + 1) * H + lane] = f2bf(o);
    float ta = o * va[lane], tb = o * vb[lane];  // f32-exact logit scalars
#pragma unroll
    for (int q = 32; q > 0; q >>= 1) {
        ta += __shfl_xor(ta, q, 64);
        tb += __shfl_xor(tb, q, 64);
    }
    if (lane == 0) { t1B[n + 1] = ta; t2B[n + 1] = tb; }
}

// ---------------------------------------------------------------------------
// GAT iter 2. All 32 row gathers hit ONE 6.4MB bf16 table (hp2bf);
// W_gat/Wm_gat applied once per node from L1-resident tables.
// ---------------------------------------------------------------------------
__global__ __launch_bounds__(256) void k_gat2(
    const int* __restrict__ sse, const int* __restrict__ bsc,
    const int* __restrict__ sue,
    const float* __restrict__ t1B, const float* __restrict__ t2B,
    const unsigned short* __restrict__ hp2bf,
    const float* __restrict__ W_gat, const float* __restrict__ Wm_gat,
    float* __restrict__ hp3)
{
    int wave = threadIdx.x >> 6;
    int lane = threadIdx.x & 63;
    int n = blockIdx.x * 4 + wave;
    if (n == 0) hp3[lane] = 0.f;
    if (n >= N_NODES) return;

    int kidx = 0, ksu = 0;
    float lg = NEG_INF_F;
    if (lane < K_NB) {
        kidx = sse[n * K_NB + lane];
        int ke = bsc[n * K_NB + lane];
        ksu = sue[ke];                     // row 0 = zero row for masked edges
        float p = t1B[kidx] + t2B[ksu];
        p = (p > 0.f) ? p : 0.2f * p;
        lg = (kidx == 0) ? NEG_INF_F : p;
    }

    unsigned wn_u[K_NB], wm_u[K_NB];
    int off = lane * 2;
#pragma unroll
    for (int k = 0; k < K_NB; ++k) {
        const unsigned short* pk = hp2bf + (size_t)readlane_i(kidx, k) * H;
        GLOAD_U16(wn_u[k], off, pk);
    }
#pragma unroll
    for (int k = 0; k < K_NB; ++k) {
        const unsigned short* ps = hp2bf + (size_t)readlane_i(ksu, k) * H;
        GLOAD_U16(wm_u[k], off, ps);
    }

    float m = lg;
#pragma unroll
    for (int o = 8; o > 0; o >>= 1) m = fmaxf(m, __shfl_xor(m, o, 64));
    float ex = __expf(lg - m);
    float s = ex;
#pragma unroll
    for (int o = 8; o > 0; o >>= 1) s += __shfl_xor(s, o, 64);
    float alpha = ex / s;

    DRAIN16(wn_u);
    HOLD16(wm_u);

    float gn = 0.f, gm = 0.f;              // alpha-weighted hp2 rows (64-dim)
#pragma unroll
    for (int k = 0; k < K_NB; ++k) {
        float ak = readlane_f(alpha, k);
        gn += ak * bf2f(wn_u[k]);
        gm += ak * bf2f(wm_u[k]);
    }
    float acc = 0.f;
#pragma unroll
    for (int j = 0; j < H; ++j) {
        acc += readlane_f(gn, j) * W_gat[j * H + lane];
        acc += readlane_f(gm, j) * Wm_gat[j * H + lane];
    }
    float o = (acc > 0.f) ? acc : expm1f(acc);
    hp3[(size_t)(n + 1) * H + lane] = o;
}

// ---------------------------------------------------------------------------
// out[b] = sum_m hp3[l_scope[b,m]] — 48 raw asm gathers all in flight.
// ---------------------------------------------------------------------------
__global__ __launch_bounds__(256) void k_out(
    const int* __restrict__ l_scope, const float* __restrict__ hp,
    float* __restrict__ out)
{
    int wave = threadIdx.x >> 6;
    int lane = threadIdx.x & 63;
    int b = blockIdx.x * 4 + wave;
    if (b >= B_MOL) return;
    int idx48 = (lane < MAXM_M) ? l_scope[b * MAXM_M + lane] : 0;
    float v[MAXM_M];
    int off = lane * 4;
#pragma unroll
    for (int m = 0; m < MAXM_M; ++m) {
        const float* pm = hp + (size_t)readlane_i(idx48, m) * H;
        GLOAD_F32(v[m], off, pm);
    }
    asm volatile("s_waitcnt vmcnt(0)"
        : "+v"(v[0]), "+v"(v[1]), "+v"(v[2]), "+v"(v[3]),
          "+v"(v[4]), "+v"(v[5]), "+v"(v[6]), "+v"(v[7]),
          "+v"(v[8]), "+v"(v[9]), "+v"(v[10]), "+v"(v[11]),
          "+v"(v[12]), "+v"(v[13]), "+v"(v[14]), "+v"(v[15]));
    asm volatile(""
        : "+v"(v[16]), "+v"(v[17]), "+v"(v[18]), "+v"(v[19]),
          "+v"(v[20]), "+v"(v[21]), "+v"(v[22]), "+v"(v[23]),
          "+v"(v[24]), "+v"(v[25]), "+v"(v[26]), "+v"(v[27]),
          "+v"(v[28]), "+v"(v[29]), "+v"(v[30]), "+v"(v[31]));
    asm volatile(""
        : "+v"(v[32]), "+v"(v[33]), "+v"(v[34]), "+v"(v[35]),
          "+v"(v[36]), "+v"(v[37]), "+v"(v[38]), "+v"(v[39]),
          "+v"(v[40]), "+v"(v[41]), "+v"(v[42]), "+v"(v[43]),
          "+v"(v[44]), "+v"(v[45]), "+v"(v[46]), "+v"(v[47]));
    float acc = 0.f;
#pragma unroll
    for (int m = 0; m < MAXM_M; ++m) acc += v[m];
    out[b * H + lane] = acc;
}

extern "C" void kernel_launch(void* const* d_in, const int* in_sizes, int n_in,
                              void* d_out, int out_size, void* d_ws, size_t ws_size,
                              hipStream_t stream)
{
    const float* tf     = (const float*)d_in[0];
    const float* fdg    = (const float*)d_in[1];
    const float* rij    = (const float*)d_in[2];
    const int*   sse    = (const int*)d_in[3];
    const int*   bsc    = (const int*)d_in[4];
    const int*   lsc    = (const int*)d_in[5];
    const int*   su     = (const int*)d_in[6];
    const int*   sul    = (const int*)d_in[7];
    const float* W_emb  = (const float*)d_in[8];
    const float* b_emb  = (const float*)d_in[9];
    const float* W_dist = (const float*)d_in[10];
    const float* b_dist = (const float*)d_in[11];
    const float* W_gat  = (const float*)d_in[12];
    const float* Wm_gat = (const float*)d_in[13];
    const float* a_gat  = (const float*)d_in[14];
    float* out = (float*)d_out;

    char* base = (char*)d_ws;
    size_t off = 0;
    auto alloc = [&](size_t bytes) {
        char* p = base + off;
        off = (off + bytes + 255) & ~(size_t)255;
        return p;
    };
    float* W2   = (float*)alloc(640 * 4);
    float* c2   = (float*)alloc(64 * 4);
    float* W3   = (float*)alloc(640 * 4);
    float* c3   = (float*)alloc(64 * 4);
    float* wa   = (float*)alloc(16 * 4);
    float* ca   = (float*)alloc(16 * 4);
    float* va   = (float*)alloc(64 * 4);
    float* vb   = (float*)alloc(64 * 4);
    float* wv9  = (float*)alloc(16 * 4);
    float* cv   = (float*)alloc(16 * 4);
    float* t1A  = (float*)alloc((size_t)(N_NODES + 1) * 4);
    float* t1B  = (float*)alloc((size_t)(N_NODES + 1) * 4);
    float* t2B  = (float*)alloc((size_t)(N_NODES + 1) * 4);
    int*   sue  = (int*)alloc((size_t)E_EDGES * 4);
    unsigned short* tfp   = (unsigned short*)alloc((size_t)(N_NODES + 1) * 16 * 2);
    unsigned short* hp2bf = (unsigned short*)alloc((size_t)(N_NODES + 1) * H * 2);
    // emsg (25.6MB) and hp3 (12.8MB) alias: emsg dead before k_gat2 writes hp3
    char* big = alloc((size_t)E_EDGES * 32);
    unsigned short* emsg = (unsigned short*)big;
    float* hp3 = (float*)big;

    k_fold<<<dim3(1), dim3(256), 0, stream>>>(
        W_emb, b_emb, W_dist, b_dist, W_gat, Wm_gat, a_gat,
        W2, c2, W3, c3, wa, ca, va, vb, wv9, cv);

    k_pre<<<dim3(PRE_NODE_BLOCKS + EDGE_BLOCKS), dim3(256), 0, stream>>>(
        tf, fdg, rij, su, sul, wa, ca, wv9, cv, t1A, tfp, emsg, sue);

    dim3 gat_grid((N_NODES + 3) / 4);
    k_gat1<<<gat_grid, dim3(256), 0, stream>>>(
        sse, bsc, t1A, tfp, emsg, W2, c2, W3, c3, va, vb, hp2bf, t1B, t2B);

    k_gat2<<<gat_grid, dim3(256), 0, stream>>>(
        sse, bsc, sue, t1B, t2B, hp2bf, W_gat, Wm_gat, hp3);

    k_out<<<dim3(B_MOL / 4), dim3(256), 0, stream>>>(lsc, hp3, out);
}